// Round 1
// baseline (2661.247 us; speedup 1.0000x reference)
//
#include <hip/hip_runtime.h>

#define NX 1024
#define NT 64
#define NBATCH 16
#define NBPB 16          // blocks per batch
#define DXC 0.02f
#define INV_SIG 20.0f
#define BIGF 1.0e6f

__device__ __forceinline__ float gelu_f(float x) {
    return 0.5f * x * (1.0f + erff(x * 0.70710678118654752f));
}

__global__ void __launch_bounds__(256, 1) nfv_kernel(
    const float* __restrict__ grid, const float* __restrict__ dtp,
    const float* __restrict__ W0, const float* __restrict__ b0,
    const float* __restrict__ W1, const float* __restrict__ b1,
    const float* __restrict__ W2, const float* __restrict__ b2,
    const float* __restrict__ W3, const float* __restrict__ b3,
    float* __restrict__ outp, unsigned int* __restrict__ ctr)
{
    __shared__ float4 st4[NX / 4];
    __shared__ float prox_s[NX];
    __shared__ float act[64 * 65];
    __shared__ float wtotL[4], wtotR[4];
    float* st_s = (float*)st4;

    const int tid  = threadIdx.x;
    const int lane = tid & 63;
    const int wid  = tid >> 6;
    const int b    = blockIdx.x >> 4;     // batch
    const int bb   = blockIdx.x & 15;     // block within batch
    const int cell = tid & 63;            // local cell
    const int oq   = tid >> 6;            // output quarter (16 outputs each)
    const int gi   = bb * 64 + cell;      // global cell
    const float dtv = dtp[b];
    const float r   = dtv / DXC;

    const float* grow = grid + (size_t)b * (NT * NX);
    float*       orow = outp + (size_t)b * (NT * NX);

    // t = 0 output = initial state
    if (tid < 64) orow[gi] = grow[gi];

    for (int t = 1; t < NT; ++t) {
        // ---- A: load state row t-1 into LDS ----
        const float* src = (t == 1) ? grow : (orow + (size_t)(t - 1) * NX);
        st4[tid] = ((const float4*)src)[tid];
        __syncthreads();

        // ---- C: shock proximity via prefix/suffix min scans ----
        const int e0 = tid * 4;
        float sm1 = st_s[(e0 == 0) ? 0 : (e0 - 1)];
        float s0v = st_s[e0], s1v = st_s[e0 + 1], s2v = st_s[e0 + 2], s3v = st_s[e0 + 3];
        float s4v = st_s[(e0 + 4 > NX - 1) ? (NX - 1) : (e0 + 4)];
        // pl[e] = shock(e-1) ? (0.5-e)*dx : BIG   (shock(j) = st[j+1] > st[j])
        float a0 = (e0 >= 1 && s0v > sm1) ? (0.5f - (float)(e0    )) * DXC : BIGF;
        float a1 = (           s1v > s0v) ? (0.5f - (float)(e0 + 1)) * DXC : BIGF;
        float a2 = (           s2v > s1v) ? (0.5f - (float)(e0 + 2)) * DXC : BIGF;
        float a3 = (           s3v > s2v) ? (0.5f - (float)(e0 + 3)) * DXC : BIGF;
        // pr[e] = shock(e) ? (e+0.5)*dx : BIG
        float r0 = (s1v > s0v) ? ((float)(e0    ) + 0.5f) * DXC : BIGF;
        float r1 = (s2v > s1v) ? ((float)(e0 + 1) + 0.5f) * DXC : BIGF;
        float r2 = (s3v > s2v) ? ((float)(e0 + 2) + 0.5f) * DXC : BIGF;
        float r3 = (e0 + 3 <= NX - 2 && s4v > s3v) ? ((float)(e0 + 3) + 0.5f) * DXC : BIGF;

        // per-thread serial inclusive prefix mins
        float m0 = a0, m1 = fminf(m0, a1), m2 = fminf(m1, a2), m3 = fminf(m2, a3);
        float TL = m3;
        #pragma unroll
        for (int off = 1; off < 64; off <<= 1) {
            float u = __shfl_up(TL, off);
            if (lane >= off) TL = fminf(TL, u);
        }
        float texL = __shfl_up(TL, 1); if (lane == 0) texL = BIGF;

        // per-thread serial suffix mins
        float q3 = r3, q2 = fminf(r2, q3), q1 = fminf(r1, q2), q0 = fminf(r0, q1);
        float TR = q0;
        #pragma unroll
        for (int off = 1; off < 64; off <<= 1) {
            float u = __shfl_down(TR, off);
            if (lane < 64 - off) TR = fminf(TR, u);
        }
        float texR = __shfl_down(TR, 1); if (lane == 63) texR = BIGF;

        if (lane == 63) wtotL[wid] = TL;
        if (lane == 0)  wtotR[wid] = TR;
        __syncthreads();
        float baseL = BIGF, baseR = BIGF;
        #pragma unroll
        for (int w = 0; w < 4; ++w) {
            if (w < wid) baseL = fminf(baseL, wtotL[w]);
            if (w > wid) baseR = fminf(baseR, wtotR[w]);
        }
        float preL = fminf(baseL, texL);
        float preR = fminf(baseR, texR);

        {
            float pm, sm, d;
            pm = fminf(preL, m0); sm = fminf(preR, q0);
            d = fminf((float)(e0    ) * DXC + pm, sm - (float)(e0    ) * DXC);
            prox_s[e0    ] = expf(-d * INV_SIG);
            pm = fminf(preL, m1); sm = fminf(preR, q1);
            d = fminf((float)(e0 + 1) * DXC + pm, sm - (float)(e0 + 1) * DXC);
            prox_s[e0 + 1] = expf(-d * INV_SIG);
            pm = fminf(preL, m2); sm = fminf(preR, q2);
            d = fminf((float)(e0 + 2) * DXC + pm, sm - (float)(e0 + 2) * DXC);
            prox_s[e0 + 2] = expf(-d * INV_SIG);
            pm = fminf(preL, m3); sm = fminf(preR, q3);
            d = fminf((float)(e0 + 3) * DXC + pm, sm - (float)(e0 + 3) * DXC);
            prox_s[e0 + 3] = expf(-d * INV_SIG);
        }
        __syncthreads();

        // ---- D: features + layer 0 ----
        float f[22];
        {
            int basei = gi - 3;
            #pragma unroll
            for (int k = 0; k < 7; ++k) {
                int ii = basei + k;
                ii = ii < 0 ? 0 : (ii > NX - 1 ? NX - 1 : ii);
                float sv = st_s[ii];
                f[k]      = sv;
                f[7 + k]  = 1.0f - 2.0f * sv;
                f[14 + k] = prox_s[ii];
            }
            f[21] = dtv;
        }
        {
            const int ob = __builtin_amdgcn_readfirstlane(oq * 16);
            #pragma unroll
            for (int oo = 0; oo < 16; oo += 4) {
                int o0 = ob + oo;
                const float* w = W0 + o0 * 22;
                float acc0 = b0[o0], acc1 = b0[o0 + 1], acc2 = b0[o0 + 2], acc3 = b0[o0 + 3];
                #pragma unroll
                for (int c = 0; c < 22; ++c) {
                    float fv = f[c];
                    acc0 += w[c]      * fv;
                    acc1 += w[22 + c] * fv;
                    acc2 += w[44 + c] * fv;
                    acc3 += w[66 + c] * fv;
                }
                act[cell * 65 + o0    ] = gelu_f(acc0);
                act[cell * 65 + o0 + 1] = gelu_f(acc1);
                act[cell * 65 + o0 + 2] = gelu_f(acc2);
                act[cell * 65 + o0 + 3] = gelu_f(acc3);
            }
        }
        __syncthreads();

        // ---- E/F: layers 1 and 2 ----
        for (int L = 0; L < 2; ++L) {
            const float* W  = (L == 0) ? W1 : W2;
            const float* bi = (L == 0) ? b1 : b2;
            float g[64];
            #pragma unroll
            for (int c = 0; c < 64; ++c) g[c] = act[cell * 65 + c];
            __syncthreads();   // everyone finished reading before overwrites
            const int ob = __builtin_amdgcn_readfirstlane(oq * 16);
            #pragma unroll
            for (int oo = 0; oo < 16; oo += 4) {
                int o0 = ob + oo;
                const float* w = W + o0 * 64;
                float acc0 = bi[o0], acc1 = bi[o0 + 1], acc2 = bi[o0 + 2], acc3 = bi[o0 + 3];
                #pragma unroll
                for (int c = 0; c < 64; ++c) {
                    float gv = g[c];
                    acc0 += w[c]       * gv;
                    acc1 += w[64 + c]  * gv;
                    acc2 += w[128 + c] * gv;
                    acc3 += w[192 + c] * gv;
                }
                act[cell * 65 + o0    ] = gelu_f(acc0);
                act[cell * 65 + o0 + 1] = gelu_f(acc1);
                act[cell * 65 + o0 + 2] = gelu_f(acc2);
                act[cell * 65 + o0 + 3] = gelu_f(acc3);
            }
            __syncthreads();
        }

        // ---- G: layer 3 + state update ----
        if (tid < 64) {
            float acc = b3[0];
            #pragma unroll
            for (int c = 0; c < 64; ++c) acc += W3[c] * act[cell * 65 + c];
            float ns = st_s[gi] + r * acc;
            ns = fminf(1.0f, fmaxf(0.0f, ns));
            orow[(size_t)t * NX + gi] = ns;
        }
        __syncthreads();

        // ---- H: per-batch cross-block barrier (one-shot counters) ----
        if (t < NT - 1) {
            if (lane == 0) {
                unsigned int* c = &ctr[b * (NT - 1) + (t - 1)];
                if (tid == 0) {
                    __hip_atomic_fetch_add(c, 1u, __ATOMIC_RELEASE, __HIP_MEMORY_SCOPE_AGENT);
                }
                while (__hip_atomic_load(c, __ATOMIC_ACQUIRE, __HIP_MEMORY_SCOPE_AGENT) < NBPB) {
                    __builtin_amdgcn_s_sleep(2);
                }
            }
            // each wave independently acquired; proceeds to reload state
        }
    }
}

extern "C" void kernel_launch(void* const* d_in, const int* in_sizes, int n_in,
                              void* d_out, int out_size, void* d_ws, size_t ws_size,
                              hipStream_t stream) {
    const float* grid = (const float*)d_in[0];
    const float* dtp  = (const float*)d_in[1];
    const float* W0   = (const float*)d_in[2];
    const float* b0   = (const float*)d_in[3];
    const float* W1   = (const float*)d_in[4];
    const float* b1   = (const float*)d_in[5];
    const float* W2   = (const float*)d_in[6];
    const float* b2   = (const float*)d_in[7];
    const float* W3   = (const float*)d_in[8];
    const float* b3   = (const float*)d_in[9];
    float* outp = (float*)d_out;
    unsigned int* ctrp = (unsigned int*)d_ws;

    // zero the one-shot barrier counters (required every launch)
    hipMemsetAsync(d_ws, 0, NBATCH * (NT - 1) * sizeof(unsigned int), stream);

    void* args[] = {(void*)&grid, (void*)&dtp, (void*)&W0, (void*)&b0,
                    (void*)&W1, (void*)&b1, (void*)&W2, (void*)&b2,
                    (void*)&W3, (void*)&b3, (void*)&outp, (void*)&ctrp};
    hipLaunchCooperativeKernel((const void*)nfv_kernel,
                               dim3(NBATCH * NBPB), dim3(256), args, 0, stream);
}

// Round 2
// 1360.008 us; speedup vs baseline: 1.9568x; 1.9568x over previous
//
#include <hip/hip_runtime.h>

#define NX 1024
#define NT 64
#define NBATCH 16
#define NBPB 16          // blocks per batch
#define DXC 0.02f
#define INV_SIG 20.0f
#define BIGF 1.0e6f

// Exact-GELU via Abramowitz-Stegun 7.1.26 erf (|err| <= 1.5e-7).
__device__ __forceinline__ float fast_gelu(float x) {
    float z = fabsf(x) * 0.70710678118654752f;
    float t = __builtin_amdgcn_rcpf(fmaf(0.3275911f, z, 1.0f));
    float p = fmaf(t, 1.061405429f, -1.453152027f);
    p = fmaf(t, p, 1.421413741f);
    p = fmaf(t, p, -0.284496736f);
    p = fmaf(t, p, 0.254829592f);
    p = p * t;
    float e = __expf(-z * z);
    float erf_abs = fmaf(-p, e, 1.0f);
    return 0.5f * x * (1.0f + copysignf(erf_abs, x));
}

__global__ void __launch_bounds__(1024, 1) nfv_kernel(
    const float* __restrict__ grid, const float* __restrict__ dtp,
    const float* __restrict__ W0, const float* __restrict__ b0,
    const float* __restrict__ W1, const float* __restrict__ b1,
    const float* __restrict__ W2, const float* __restrict__ b2,
    const float* __restrict__ W3, const float* __restrict__ b3,
    float* __restrict__ outp, unsigned int* __restrict__ ctr)
{
    __shared__ float st_s[NX];
    __shared__ float prox_s[NX];
    __shared__ float act[64 * 65];
    __shared__ float wtotL[16], wtotR[16];

    const int tid  = threadIdx.x;
    const int lane = tid & 63;
    const int wid  = tid >> 6;
    const int b    = blockIdx.x >> 4;     // batch
    const int bb   = blockIdx.x & 15;     // block within batch
    const int cell = lane;                // local cell (0..63)
    const int gi   = bb * 64 + cell;      // global cell for MLP
    const float dtv = dtp[b];
    const float r   = dtv / DXC;
    const int o0   = __builtin_amdgcn_readfirstlane(wid * 4);  // 4 outputs/thread

    const float* grow = grid + (size_t)b * (NT * NX);
    float*       orow = outp + (size_t)b * (NT * NX);

    // t = 0 output row (all 16 blocks write identical values — benign)
    orow[tid] = grow[tid];

    for (int t = 1; t < NT; ++t) {
        // ---- A: load state row t-1 into LDS (1 float/thread, coalesced) ----
        const float* src = (t == 1) ? grow : (orow + (size_t)(t - 1) * NX);
        st_s[tid] = src[tid];
        __syncthreads();

        // ---- B: shock proximity via prefix/suffix min scans (1 cell/thread) ----
        {
            const int e = tid;
            float s0  = st_s[e];
            float sm1 = (e >= 1)      ? st_s[e - 1] : s0;
            float s1  = (e <= NX - 2) ? st_s[e + 1] : s0;
            // shock(j) <=> st[j+1] > st[j]  (both RH conditions reduce to rR > rL)
            float aL = (e >= 1      && s0 > sm1) ? (0.5f - (float)e) * DXC : BIGF;
            float aR = (e <= NX - 2 && s1 > s0)  ? ((float)e + 0.5f) * DXC : BIGF;

            float TL = aL;                      // wave inclusive prefix-min
            #pragma unroll
            for (int off = 1; off < 64; off <<= 1) {
                float u = __shfl_up(TL, off);
                if (lane >= off) TL = fminf(TL, u);
            }
            float TR = aR;                      // wave inclusive suffix-min
            #pragma unroll
            for (int off = 1; off < 64; off <<= 1) {
                float u = __shfl_down(TR, off);
                if (lane < 64 - off) TR = fminf(TR, u);
            }
            if (lane == 63) wtotL[wid] = TL;
            if (lane == 0)  wtotR[wid] = TR;
            __syncthreads();
            float baseL = BIGF, baseR = BIGF;
            #pragma unroll
            for (int w = 0; w < 16; ++w) {
                if (w < wid) baseL = fminf(baseL, wtotL[w]);
                if (w > wid) baseR = fminf(baseR, wtotR[w]);
            }
            float pmin = fminf(baseL, TL);
            float smin = fminf(baseR, TR);
            float xc = (float)e * DXC;
            float d = fminf(xc + pmin, smin - xc);
            prox_s[e] = __expf(-d * INV_SIG);
        }
        __syncthreads();

        // ---- C: features + layer 0 (4 outputs/thread) ----
        float f[22];
        {
            int basei = gi - 3;
            #pragma unroll
            for (int k = 0; k < 7; ++k) {
                int ii = basei + k;
                ii = ii < 0 ? 0 : (ii > NX - 1 ? NX - 1 : ii);
                float sv = st_s[ii];
                f[k]      = sv;
                f[7 + k]  = 1.0f - 2.0f * sv;
                f[14 + k] = prox_s[ii];
            }
            f[21] = dtv;
        }
        {
            const float* w = W0 + o0 * 22;
            float acc0 = b0[o0], acc1 = b0[o0 + 1], acc2 = b0[o0 + 2], acc3 = b0[o0 + 3];
            #pragma unroll
            for (int c = 0; c < 22; ++c) {
                float fv = f[c];
                acc0 += w[c]      * fv;
                acc1 += w[22 + c] * fv;
                acc2 += w[44 + c] * fv;
                acc3 += w[66 + c] * fv;
            }
            act[cell * 65 + o0    ] = fast_gelu(acc0);
            act[cell * 65 + o0 + 1] = fast_gelu(acc1);
            act[cell * 65 + o0 + 2] = fast_gelu(acc2);
            act[cell * 65 + o0 + 3] = fast_gelu(acc3);
        }
        __syncthreads();

        // ---- D: layers 1 and 2 ----
        #pragma unroll
        for (int L = 0; L < 2; ++L) {
            const float* W  = (L == 0) ? W1 : W2;
            const float* bi = (L == 0) ? b1 : b2;
            float g[64];
            #pragma unroll
            for (int c = 0; c < 64; ++c) g[c] = act[cell * 65 + c];
            __syncthreads();   // everyone finished reading before overwrite
            const float* w = W + o0 * 64;
            float acc0 = bi[o0], acc1 = bi[o0 + 1], acc2 = bi[o0 + 2], acc3 = bi[o0 + 3];
            #pragma unroll
            for (int c = 0; c < 64; ++c) {
                float gv = g[c];
                acc0 += w[c]       * gv;
                acc1 += w[64 + c]  * gv;
                acc2 += w[128 + c] * gv;
                acc3 += w[192 + c] * gv;
            }
            act[cell * 65 + o0    ] = fast_gelu(acc0);
            act[cell * 65 + o0 + 1] = fast_gelu(acc1);
            act[cell * 65 + o0 + 2] = fast_gelu(acc2);
            act[cell * 65 + o0 + 3] = fast_gelu(acc3);
            __syncthreads();
        }

        // ---- E: layer 3 + state update (wave 0 only) ----
        if (tid < 64) {
            float acc = b3[0];
            #pragma unroll
            for (int c = 0; c < 64; ++c) acc += W3[c] * act[cell * 65 + c];
            float ns = st_s[gi] + r * acc;
            ns = fminf(1.0f, fmaxf(0.0f, ns));
            orow[(size_t)t * NX + gi] = ns;
        }

        // ---- F: per-batch cross-block barrier (grid.sync pattern) ----
        if (t < NT - 1) {
            if (tid == 0) {
                unsigned int* c = &ctr[b * (NT - 1) + (t - 1)];
                __hip_atomic_fetch_add(c, 1u, __ATOMIC_RELEASE, __HIP_MEMORY_SCOPE_AGENT);
                while (__hip_atomic_load(c, __ATOMIC_ACQUIRE, __HIP_MEMORY_SCOPE_AGENT) < NBPB) {
                    __builtin_amdgcn_s_sleep(1);
                }
            }
            __syncthreads();
        }
    }
}

extern "C" void kernel_launch(void* const* d_in, const int* in_sizes, int n_in,
                              void* d_out, int out_size, void* d_ws, size_t ws_size,
                              hipStream_t stream) {
    const float* grid = (const float*)d_in[0];
    const float* dtp  = (const float*)d_in[1];
    const float* W0   = (const float*)d_in[2];
    const float* b0   = (const float*)d_in[3];
    const float* W1   = (const float*)d_in[4];
    const float* b1   = (const float*)d_in[5];
    const float* W2   = (const float*)d_in[6];
    const float* b2   = (const float*)d_in[7];
    const float* W3   = (const float*)d_in[8];
    const float* b3   = (const float*)d_in[9];
    float* outp = (float*)d_out;
    unsigned int* ctrp = (unsigned int*)d_ws;

    hipMemsetAsync(d_ws, 0, NBATCH * (NT - 1) * sizeof(unsigned int), stream);

    void* args[] = {(void*)&grid, (void*)&dtp, (void*)&W0, (void*)&b0,
                    (void*)&W1, (void*)&b1, (void*)&W2, (void*)&b2,
                    (void*)&W3, (void*)&b3, (void*)&outp, (void*)&ctrp};
    hipLaunchCooperativeKernel((const void*)nfv_kernel,
                               dim3(NBATCH * NBPB), dim3(1024), args, 0, stream);
}

// Round 3
// 1217.129 us; speedup vs baseline: 2.1865x; 1.1174x over previous
//
#include <hip/hip_runtime.h>

#define NX 1024
#define NT 64
#define NBATCH 16
#define NBPB 16          // blocks per batch (64 cells each)
#define DXC 0.02f
#define INV_SIG 20.0f
#define BIGF 1.0e6f

// Exact-GELU via Abramowitz-Stegun 7.1.26 erf (|err| <= 1.5e-7).
__device__ __forceinline__ float fast_gelu(float x) {
    float z = fabsf(x) * 0.70710678118654752f;
    float t = __builtin_amdgcn_rcpf(fmaf(0.3275911f, z, 1.0f));
    float p = fmaf(t, 1.061405429f, -1.453152027f);
    p = fmaf(t, p, 1.421413741f);
    p = fmaf(t, p, -0.284496736f);
    p = fmaf(t, p, 0.254829592f);
    p = p * t;
    float e = __expf(-z * z);
    float erf_abs = fmaf(-p, e, 1.0f);
    return 0.5f * x * (1.0f + copysignf(erf_abs, x));
}

__global__ void __launch_bounds__(1024, 1) nfv_kernel(
    const float* __restrict__ grid, const float* __restrict__ dtp,
    const float* __restrict__ W0, const float* __restrict__ b0,
    const float* __restrict__ W1, const float* __restrict__ b1,
    const float* __restrict__ W2, const float* __restrict__ b2,
    const float* __restrict__ W3, const float* __restrict__ b3,
    float* __restrict__ outp, unsigned int* __restrict__ flags)
{
    __shared__ float st_s[128];     // state strip [c0-32, c0+95] (clamped)
    __shared__ float prox_s[128];   // prox over the strip
    __shared__ float actA[64 * 65];
    __shared__ float actB[64 * 65];

    const int tid  = threadIdx.x;
    const int lane = tid & 63;
    const int wid  = tid >> 6;
    const int b    = blockIdx.x >> 4;     // batch
    const int bb   = blockIdx.x & 15;     // block within batch
    const int cell = lane;                // local cell (0..63)
    const int c0   = bb * 64;
    const int gi   = c0 + cell;           // global cell
    const float dtv = dtp[b];
    const float r   = dtv / DXC;
    const float b3v = b3[0];
    const int o0   = __builtin_amdgcn_readfirstlane(wid * 4);  // 4 outputs/thread

    const float* grow = grid + (size_t)b * (NT * NX);
    float*       orow = outp + (size_t)b * (NT * NX);

    // t = 0 output: each block writes its own 64 cells
    if (tid < 64) orow[c0 + tid] = grow[c0 + tid];

    for (int t = 1; t < NT; ++t) {
        // ---- S0: neighbor-flag wait (row t-1 ready at bb-1 / bb+1) ----
        if (t >= 2) {
            if (tid == 0 && bb > 0) {
                const unsigned int* fl = &flags[blockIdx.x - 1];
                while (__hip_atomic_load(fl, __ATOMIC_ACQUIRE, __HIP_MEMORY_SCOPE_AGENT) < (unsigned)(t - 1))
                    __builtin_amdgcn_s_sleep(1);
            }
            if (tid == 64 && bb < NBPB - 1) {
                const unsigned int* fr = &flags[blockIdx.x + 1];
                while (__hip_atomic_load(fr, __ATOMIC_ACQUIRE, __HIP_MEMORY_SCOPE_AGENT) < (unsigned)(t - 1))
                    __builtin_amdgcn_s_sleep(1);
            }
        }
        __syncthreads();   // S1: flags acquired; also guards st_s/actB reuse

        // ---- wave0: strip load + shock scan + prox (no block sync inside) ----
        if (wid == 0) {
            const float* src = (t == 1) ? grow : (orow + (size_t)(t - 1) * NX);
            int ga = c0 - 32 + lane;        ga = ga < 0 ? 0 : (ga > NX - 1 ? NX - 1 : ga);
            int gb = c0 + 32 + lane;        gb = gb > NX - 1 ? NX - 1 : gb;
            st_s[lane]      = src[ga];
            st_s[lane + 64] = src[gb];
            asm volatile("s_waitcnt lgkmcnt(0)" ::: "memory");  // wave-internal LDS visibility

            const int j0 = 2 * lane, j1 = j0 + 1;
            const int g0 = c0 - 32 + j0, g1 = g0 + 1;
            float sjm1 = (j0 >= 1)  ? st_s[j0 - 1] : BIGF;
            float s0v  = st_s[j0];
            float s1v  = st_s[j1];
            float sp2  = (j1 < 127) ? st_s[j1 + 1] : -BIGF;
            // shock(j) <=> st[j+1] > st[j]; clamped edge loads make boundary cases false
            float aL0 = (j0 >= 1 && s0v > sjm1) ? (0.5f - (float)g0) * DXC : BIGF;
            float aL1 = (s1v > s0v)             ? (0.5f - (float)g1) * DXC : BIGF;
            float aR0 = (s1v > s0v)             ? ((float)g0 + 0.5f) * DXC : BIGF;
            float aR1 = (j1 < 127 && sp2 > s1v) ? ((float)g1 + 0.5f) * DXC : BIGF;

            // inclusive prefix-min over pair-mins
            float m0 = aL0, m1 = fminf(aL0, aL1);
            float T = m1;
            #pragma unroll
            for (int off = 1; off < 64; off <<= 1) {
                float u = __shfl_up(T, off);
                if (lane >= off) T = fminf(T, u);
            }
            float ex = __shfl_up(T, 1); if (lane == 0) ex = BIGF;
            float p0 = fminf(ex, m0), p1 = fminf(ex, m1);
            // inclusive suffix-min
            float q1 = aR1, q0 = fminf(aR0, aR1);
            float S = q0;
            #pragma unroll
            for (int off = 1; off < 64; off <<= 1) {
                float u = __shfl_down(S, off);
                if (lane < 64 - off) S = fminf(S, u);
            }
            float sx = __shfl_down(S, 1); if (lane == 63) sx = BIGF;
            float sm0 = fminf(sx, q0), sm1 = fminf(sx, q1);

            float x0 = (float)g0 * DXC, x1 = (float)g1 * DXC;
            prox_s[j0] = __expf(-fminf(x0 + p0, sm0 - x0) * INV_SIG);
            prox_s[j1] = __expf(-fminf(x1 + p1, sm1 - x1) * INV_SIG);
        }
        __syncthreads();   // S2: strip + prox ready

        // ---- features + layer 0 -> actA ----
        float f[22];
        {
            #pragma unroll
            for (int k = 0; k < 7; ++k) {
                int ii = gi - 3 + k;
                ii = ii < 0 ? 0 : (ii > NX - 1 ? NX - 1 : ii);
                int si = ii - c0 + 32;
                float sv = st_s[si];
                f[k]      = sv;
                f[7 + k]  = 1.0f - 2.0f * sv;
                f[14 + k] = prox_s[si];
            }
            f[21] = dtv;
        }
        {
            const float* w = W0 + o0 * 22;
            float acc0 = b0[o0], acc1 = b0[o0 + 1], acc2 = b0[o0 + 2], acc3 = b0[o0 + 3];
            #pragma unroll
            for (int c = 0; c < 22; ++c) {
                float fv = f[c];
                acc0 += w[c]      * fv;
                acc1 += w[22 + c] * fv;
                acc2 += w[44 + c] * fv;
                acc3 += w[66 + c] * fv;
            }
            actA[cell * 65 + o0    ] = fast_gelu(acc0);
            actA[cell * 65 + o0 + 1] = fast_gelu(acc1);
            actA[cell * 65 + o0 + 2] = fast_gelu(acc2);
            actA[cell * 65 + o0 + 3] = fast_gelu(acc3);
        }
        __syncthreads();   // S3

        // ---- layer 1: actA -> actB ----
        {
            const float* w = W1 + o0 * 64;
            float acc0 = b1[o0], acc1 = b1[o0 + 1], acc2 = b1[o0 + 2], acc3 = b1[o0 + 3];
            #pragma unroll
            for (int c = 0; c < 64; ++c) {
                float gv = actA[cell * 65 + c];
                acc0 += w[c]       * gv;
                acc1 += w[64 + c]  * gv;
                acc2 += w[128 + c] * gv;
                acc3 += w[192 + c] * gv;
            }
            actB[cell * 65 + o0    ] = fast_gelu(acc0);
            actB[cell * 65 + o0 + 1] = fast_gelu(acc1);
            actB[cell * 65 + o0 + 2] = fast_gelu(acc2);
            actB[cell * 65 + o0 + 3] = fast_gelu(acc3);
        }
        __syncthreads();   // S4

        // ---- layer 2: actB -> actA ----
        {
            const float* w = W2 + o0 * 64;
            float acc0 = b2[o0], acc1 = b2[o0 + 1], acc2 = b2[o0 + 2], acc3 = b2[o0 + 3];
            #pragma unroll
            for (int c = 0; c < 64; ++c) {
                float gv = actB[cell * 65 + c];
                acc0 += w[c]       * gv;
                acc1 += w[64 + c]  * gv;
                acc2 += w[128 + c] * gv;
                acc3 += w[192 + c] * gv;
            }
            actA[cell * 65 + o0    ] = fast_gelu(acc0);
            actA[cell * 65 + o0 + 1] = fast_gelu(acc1);
            actA[cell * 65 + o0 + 2] = fast_gelu(acc2);
            actA[cell * 65 + o0 + 3] = fast_gelu(acc3);
        }
        __syncthreads();   // S5

        // ---- layer 3 partials: 16 waves x 4 channels -> actB[cell*65 + wid] ----
        {
            float ps = W3[o0]     * actA[cell * 65 + o0]
                     + W3[o0 + 1] * actA[cell * 65 + o0 + 1]
                     + W3[o0 + 2] * actA[cell * 65 + o0 + 2]
                     + W3[o0 + 3] * actA[cell * 65 + o0 + 3];
            actB[cell * 65 + wid] = ps;
        }
        __syncthreads();   // S6

        // ---- wave0: reduce + state update + store + flag release ----
        if (wid == 0) {
            float sum = 0.0f;
            #pragma unroll
            for (int w = 0; w < 16; ++w) sum += actB[lane * 65 + w];
            float ns = st_s[lane + 32] + r * (sum + b3v);
            ns = fminf(1.0f, fmaxf(0.0f, ns));
            orow[(size_t)t * NX + gi] = ns;
            if (lane == 0 && t < NT - 1) {
                __hip_atomic_store(&flags[blockIdx.x], (unsigned)t,
                                   __ATOMIC_RELEASE, __HIP_MEMORY_SCOPE_AGENT);
            }
        }
        // next iteration's S1 guards st_s/actB overwrite vs wave0's reads above
    }
}

extern "C" void kernel_launch(void* const* d_in, const int* in_sizes, int n_in,
                              void* d_out, int out_size, void* d_ws, size_t ws_size,
                              hipStream_t stream) {
    const float* grid = (const float*)d_in[0];
    const float* dtp  = (const float*)d_in[1];
    const float* W0   = (const float*)d_in[2];
    const float* b0   = (const float*)d_in[3];
    const float* W1   = (const float*)d_in[4];
    const float* b1   = (const float*)d_in[5];
    const float* W2   = (const float*)d_in[6];
    const float* b2   = (const float*)d_in[7];
    const float* W3   = (const float*)d_in[8];
    const float* b3   = (const float*)d_in[9];
    float* outp = (float*)d_out;
    unsigned int* flagsp = (unsigned int*)d_ws;

    // zero the per-block progress flags (required every launch)
    hipMemsetAsync(d_ws, 0, NBATCH * NBPB * sizeof(unsigned int), stream);

    void* args[] = {(void*)&grid, (void*)&dtp, (void*)&W0, (void*)&b0,
                    (void*)&W1, (void*)&b1, (void*)&W2, (void*)&b2,
                    (void*)&W3, (void*)&b3, (void*)&outp, (void*)&flagsp};
    hipLaunchCooperativeKernel((const void*)nfv_kernel,
                               dim3(NBATCH * NBPB), dim3(1024), args, 0, stream);
}

// Round 4
// 790.236 us; speedup vs baseline: 3.3677x; 1.5402x over previous
//
#include <hip/hip_runtime.h>

#define NX 1024
#define NT 64
#define NBATCH 16
#define NBPB 16          // blocks per batch (64 cells each)
#define NBLK (NBATCH * NBPB)
#define DXC 0.02f
#define INV_SIG 20.0f
#define BIGF 1.0e6f

// Exact-GELU via Abramowitz-Stegun 7.1.26 erf (|err| <= 1.5e-7).
__device__ __forceinline__ float fast_gelu(float x) {
    float z = fabsf(x) * 0.70710678118654752f;
    float t = __builtin_amdgcn_rcpf(fmaf(0.3275911f, z, 1.0f));
    float p = fmaf(t, 1.061405429f, -1.453152027f);
    p = fmaf(t, p, 1.421413741f);
    p = fmaf(t, p, -0.284496736f);
    p = fmaf(t, p, 0.254829592f);
    p = p * t;
    float e = __expf(-z * z);
    float erf_abs = fmaf(-p, e, 1.0f);
    return 0.5f * x * (1.0f + copysignf(erf_abs, x));
}

// SYSTEM-scope relaxed ops: sc0+sc1 -> bypass L1/L2, no cache inv/wb emitted.
__device__ __forceinline__ float sys_load_f(const float* p) {
    return __hip_atomic_load(p, __ATOMIC_RELAXED, __HIP_MEMORY_SCOPE_SYSTEM);
}
__device__ __forceinline__ void sys_store_f(float* p, float v) {
    __hip_atomic_store(p, v, __ATOMIC_RELAXED, __HIP_MEMORY_SCOPE_SYSTEM);
}
__device__ __forceinline__ unsigned sys_load_u(const unsigned* p) {
    return __hip_atomic_load(p, __ATOMIC_RELAXED, __HIP_MEMORY_SCOPE_SYSTEM);
}
__device__ __forceinline__ void sys_store_u(unsigned* p, unsigned v) {
    __hip_atomic_store(p, v, __ATOMIC_RELAXED, __HIP_MEMORY_SCOPE_SYSTEM);
}

__global__ void __launch_bounds__(1024, 1) nfv_kernel(
    const float* __restrict__ grid, const float* __restrict__ dtp,
    const float* __restrict__ W0, const float* __restrict__ b0,
    const float* __restrict__ W1, const float* __restrict__ b1,
    const float* __restrict__ W2, const float* __restrict__ b2,
    const float* __restrict__ W3, const float* __restrict__ b3,
    float* __restrict__ outp, unsigned* __restrict__ tags,
    float* __restrict__ halo)
{
    __shared__ float st_s[128];     // state strip, global [c0-32, c0+96)
    __shared__ float prox_s[128];
    __shared__ float actA[64 * 65];
    __shared__ float actB[64 * 65];

    const int tid  = threadIdx.x;
    const int lane = tid & 63;
    const int wid  = tid >> 6;
    const int bid  = blockIdx.x;
    const int b    = bid >> 4;            // batch
    const int bb   = bid & 15;            // block within batch
    const int cell = lane;
    const int c0   = bb * 64;
    const int gi   = c0 + cell;
    const float dtv = dtp[b];
    const float r   = dtv / DXC;
    const float b3v = b3[0];
    const int o0   = __builtin_amdgcn_readfirstlane(wid * 4);

    const float* grow = grid + (size_t)b * (NT * NX);
    float*       orow = outp + (size_t)b * (NT * NX);

    if (tid < 64) orow[c0 + tid] = grow[c0 + tid];

    for (int t = 1; t < NT; ++t) {
        // ---- wave0: refresh strip (halo exchange) + shock-proximity scan ----
        if (wid == 0) {
            if (t == 1) {
                int ga = c0 - 32 + lane;  ga = ga < 0 ? 0 : ga;
                int gb = c0 + 32 + lane;  gb = gb > NX - 1 ? NX - 1 : gb;
                st_s[lane]      = grow[ga];
                st_s[lane + 64] = grow[gb];
            } else {
                const unsigned need = (unsigned)(t - 1);
                if (lane < 2) {           // lane0: left tag, lane1: right tag
                    bool has = lane ? (bb < NBPB - 1) : (bb > 0);
                    if (has) {
                        const unsigned* tp = &tags[bid + (lane ? 1 : -1)];
                        while (sys_load_u(tp) < need) __builtin_amdgcn_s_sleep(1);
                    }
                }
                // wave reconverged: neighbor halos for row t-1 are published
                const int p = (t - 1) & 1;
                const int j = lane & 31;
                if (lane < 32) {
                    float v = (bb > 0)
                        ? sys_load_f(&halo[(size_t)(bid - 1) * 128 + p * 64 + 32 + j])
                        : st_s[32];                 // clamp: global cell 0
                    st_s[j] = v;
                } else {
                    float v = (bb < NBPB - 1)
                        ? sys_load_f(&halo[(size_t)(bid + 1) * 128 + p * 64 + j])
                        : st_s[95];                 // clamp: global cell NX-1
                    st_s[96 + j] = v;
                }
            }

            // ---- strip prefix/suffix min scan -> prox ----
            const int j0 = 2 * lane, j1 = j0 + 1;
            const int g0 = c0 - 32 + j0, g1 = g0 + 1;
            float sjm1 = (j0 >= 1)  ? st_s[j0 - 1] : BIGF;
            float s0v  = st_s[j0];
            float s1v  = st_s[j1];
            float sp2  = (j1 < 127) ? st_s[j1 + 1] : -BIGF;
            float aL0 = (j0 >= 1 && s0v > sjm1) ? (0.5f - (float)g0) * DXC : BIGF;
            float aL1 = (s1v > s0v)             ? (0.5f - (float)g1) * DXC : BIGF;
            float aR0 = (s1v > s0v)             ? ((float)g0 + 0.5f) * DXC : BIGF;
            float aR1 = (j1 < 127 && sp2 > s1v) ? ((float)g1 + 0.5f) * DXC : BIGF;

            float m0 = aL0, m1 = fminf(aL0, aL1);
            float T = m1;
            #pragma unroll
            for (int off = 1; off < 64; off <<= 1) {
                float u = __shfl_up(T, off);
                if (lane >= off) T = fminf(T, u);
            }
            float ex = __shfl_up(T, 1); if (lane == 0) ex = BIGF;
            float p0 = fminf(ex, m0), p1 = fminf(ex, m1);
            float q1 = aR1, q0 = fminf(aR0, aR1);
            float S = q0;
            #pragma unroll
            for (int off = 1; off < 64; off <<= 1) {
                float u = __shfl_down(S, off);
                if (lane < 64 - off) S = fminf(S, u);
            }
            float sx = __shfl_down(S, 1); if (lane == 63) sx = BIGF;
            float sm0 = fminf(sx, q0), sm1 = fminf(sx, q1);

            float x0 = (float)g0 * DXC, x1 = (float)g1 * DXC;
            prox_s[j0] = __expf(-fminf(x0 + p0, sm0 - x0) * INV_SIG);
            prox_s[j1] = __expf(-fminf(x1 + p1, sm1 - x1) * INV_SIG);
        }
        __syncthreads();   // A: strip + prox ready

        // ---- features + layer 0 -> actA ----
        float f[22];
        {
            #pragma unroll
            for (int k = 0; k < 7; ++k) {
                int ii = gi - 3 + k;
                ii = ii < 0 ? 0 : (ii > NX - 1 ? NX - 1 : ii);
                int si = ii - c0 + 32;
                float sv = st_s[si];
                f[k]      = sv;
                f[7 + k]  = 1.0f - 2.0f * sv;
                f[14 + k] = prox_s[si];
            }
            f[21] = dtv;
        }
        {
            const float* w = W0 + o0 * 22;
            float acc0 = b0[o0], acc1 = b0[o0 + 1], acc2 = b0[o0 + 2], acc3 = b0[o0 + 3];
            #pragma unroll
            for (int c = 0; c < 22; ++c) {
                float fv = f[c];
                acc0 += w[c]      * fv;
                acc1 += w[22 + c] * fv;
                acc2 += w[44 + c] * fv;
                acc3 += w[66 + c] * fv;
            }
            actA[cell * 65 + o0    ] = fast_gelu(acc0);
            actA[cell * 65 + o0 + 1] = fast_gelu(acc1);
            actA[cell * 65 + o0 + 2] = fast_gelu(acc2);
            actA[cell * 65 + o0 + 3] = fast_gelu(acc3);
        }
        __syncthreads();   // B

        // ---- layer 1: actA -> actB ----
        {
            const float* w = W1 + o0 * 64;
            float acc0 = b1[o0], acc1 = b1[o0 + 1], acc2 = b1[o0 + 2], acc3 = b1[o0 + 3];
            #pragma unroll
            for (int c = 0; c < 64; ++c) {
                float gv = actA[cell * 65 + c];
                acc0 += w[c]       * gv;
                acc1 += w[64 + c]  * gv;
                acc2 += w[128 + c] * gv;
                acc3 += w[192 + c] * gv;
            }
            actB[cell * 65 + o0    ] = fast_gelu(acc0);
            actB[cell * 65 + o0 + 1] = fast_gelu(acc1);
            actB[cell * 65 + o0 + 2] = fast_gelu(acc2);
            actB[cell * 65 + o0 + 3] = fast_gelu(acc3);
        }
        __syncthreads();   // C

        // ---- layer 2: actB -> actA ----
        {
            const float* w = W2 + o0 * 64;
            float acc0 = b2[o0], acc1 = b2[o0 + 1], acc2 = b2[o0 + 2], acc3 = b2[o0 + 3];
            #pragma unroll
            for (int c = 0; c < 64; ++c) {
                float gv = actB[cell * 65 + c];
                acc0 += w[c]       * gv;
                acc1 += w[64 + c]  * gv;
                acc2 += w[128 + c] * gv;
                acc3 += w[192 + c] * gv;
            }
            actA[cell * 65 + o0    ] = fast_gelu(acc0);
            actA[cell * 65 + o0 + 1] = fast_gelu(acc1);
            actA[cell * 65 + o0 + 2] = fast_gelu(acc2);
            actA[cell * 65 + o0 + 3] = fast_gelu(acc3);
        }
        __syncthreads();   // D

        // ---- layer 3 partials: 16 waves x 4 channels ----
        {
            float ps = W3[o0]     * actA[cell * 65 + o0]
                     + W3[o0 + 1] * actA[cell * 65 + o0 + 1]
                     + W3[o0 + 2] * actA[cell * 65 + o0 + 2]
                     + W3[o0 + 3] * actA[cell * 65 + o0 + 3];
            actB[cell * 65 + wid] = ps;
        }
        __syncthreads();   // E

        // ---- wave0: reduce + update + store + halo publish ----
        if (wid == 0) {
            float sum = 0.0f;
            #pragma unroll
            for (int w = 0; w < 16; ++w) sum += actB[lane * 65 + w];
            float ns = st_s[lane + 32] + r * (sum + b3v);
            ns = fminf(1.0f, fmaxf(0.0f, ns));
            orow[(size_t)t * NX + gi] = ns;
            st_s[32 + lane] = ns;                  // keep own row resident in LDS
            if (t < NT - 1) {
                sys_store_f(&halo[(size_t)bid * 128 + (t & 1) * 64 + lane], ns);
                asm volatile("s_waitcnt vmcnt(0)" ::: "memory");  // halo visible before tag
                if (lane == 0) sys_store_u(&tags[bid], (unsigned)t);
            }
        }
        // next iter's sync A guards st_s/prox_s/actB reuse against waves 1-15
    }
}

extern "C" void kernel_launch(void* const* d_in, const int* in_sizes, int n_in,
                              void* d_out, int out_size, void* d_ws, size_t ws_size,
                              hipStream_t stream) {
    const float* grid = (const float*)d_in[0];
    const float* dtp  = (const float*)d_in[1];
    const float* W0   = (const float*)d_in[2];
    const float* b0   = (const float*)d_in[3];
    const float* W1   = (const float*)d_in[4];
    const float* b1   = (const float*)d_in[5];
    const float* W2   = (const float*)d_in[6];
    const float* b2   = (const float*)d_in[7];
    const float* W3   = (const float*)d_in[8];
    const float* b3   = (const float*)d_in[9];
    float* outp = (float*)d_out;

    unsigned* tags = (unsigned*)d_ws;                       // NBLK u32
    float*    halo = (float*)((char*)d_ws + 1024);          // NBLK * 2 * 64 floats

    hipMemsetAsync(d_ws, 0, 1024, stream);   // zero tags each launch

    void* args[] = {(void*)&grid, (void*)&dtp, (void*)&W0, (void*)&b0,
                    (void*)&W1, (void*)&b1, (void*)&W2, (void*)&b2,
                    (void*)&W3, (void*)&b3, (void*)&outp, (void*)&tags, (void*)&halo};
    hipLaunchCooperativeKernel((const void*)nfv_kernel,
                               dim3(NBLK), dim3(1024), args, 0, stream);
}

// Round 5
// 412.262 us; speedup vs baseline: 6.4552x; 1.9168x over previous
//
#include <hip/hip_runtime.h>

#define NX 1024
#define NT 64
#define NBATCH 16
#define NBPB 16          // blocks per batch (64 cells each)
#define NBLK (NBATCH * NBPB)
#define DXC 0.02f
#define INV_SIG 20.0f
#define BIGF 1.0e6f

typedef __attribute__((ext_vector_type(8))) short bf16x8;
typedef __attribute__((ext_vector_type(4))) float f32x4;

// round-to-nearest-even f32 -> bf16
__device__ __forceinline__ unsigned short f2bf(float x) {
    unsigned u = __builtin_bit_cast(unsigned, x);
    u += 0x7FFFu + ((u >> 16) & 1u);
    return (unsigned short)(u >> 16);
}

// Exact-GELU via Abramowitz-Stegun 7.1.26 erf (|err| <= 1.5e-7).
__device__ __forceinline__ float fast_gelu(float x) {
    float z = fabsf(x) * 0.70710678118654752f;
    float t = __builtin_amdgcn_rcpf(fmaf(0.3275911f, z, 1.0f));
    float p = fmaf(t, 1.061405429f, -1.453152027f);
    p = fmaf(t, p, 1.421413741f);
    p = fmaf(t, p, -0.284496736f);
    p = fmaf(t, p, 0.254829592f);
    p = p * t;
    float e = __expf(-z * z);
    float erf_abs = fmaf(-p, e, 1.0f);
    return 0.5f * x * (1.0f + copysignf(erf_abs, x));
}

// SYSTEM-scope relaxed ops: bypass L1/L2, no cache inv/wb emitted.
__device__ __forceinline__ float sys_load_f(const float* p) {
    return __hip_atomic_load(p, __ATOMIC_RELAXED, __HIP_MEMORY_SCOPE_SYSTEM);
}
__device__ __forceinline__ void sys_store_f(float* p, float v) {
    __hip_atomic_store(p, v, __ATOMIC_RELAXED, __HIP_MEMORY_SCOPE_SYSTEM);
}
__device__ __forceinline__ unsigned sys_load_u(const unsigned* p) {
    return __hip_atomic_load(p, __ATOMIC_RELAXED, __HIP_MEMORY_SCOPE_SYSTEM);
}
__device__ __forceinline__ void sys_store_u(unsigned* p, unsigned v) {
    __hip_atomic_store(p, v, __ATOMIC_RELAXED, __HIP_MEMORY_SCOPE_SYSTEM);
}

__global__ void __launch_bounds__(1024, 1) nfv_kernel(
    const float* __restrict__ grid, const float* __restrict__ dtp,
    const float* __restrict__ W0, const float* __restrict__ b0,
    const float* __restrict__ W1, const float* __restrict__ b1,
    const float* __restrict__ W2, const float* __restrict__ b2,
    const float* __restrict__ W3, const float* __restrict__ b3,
    float* __restrict__ outp, unsigned* __restrict__ tags,
    float* __restrict__ halo)
{
    __shared__ float st_s[128];     // state strip, global [c0-32, c0+96)
    __shared__ float prox_s[128];
    __shared__ __align__(16) unsigned short actA[64 * 72];  // bf16 acts, stride 72
    __shared__ __align__(16) unsigned short actB[64 * 72];
    __shared__ __align__(16) unsigned short w1s[64 * 72];   // bf16 W1 [out][in]
    __shared__ __align__(16) unsigned short w2s[64 * 72];
    __shared__ float bias1_s[64], bias2_s[64], w3_s[64];
    __shared__ float part_s[64 * 5];                        // L3 partials [row][tn]

    const int tid  = threadIdx.x;
    const int lane = tid & 63;
    const int wid  = tid >> 6;
    const int bid  = blockIdx.x;
    const int b    = bid >> 4;            // batch
    const int bb   = bid & 15;            // block within batch
    const int cell = lane;
    const int c0   = bb * 64;
    const int gi   = c0 + cell;
    const float dtv = dtp[b];
    const float r   = dtv / DXC;
    const float b3v = b3[0];
    const int o0   = __builtin_amdgcn_readfirstlane(wid * 4);

    const float* grow = grid + (size_t)b * (NT * NX);
    float*       orow = outp + (size_t)b * (NT * NX);

    // ---- prologue: weights -> bf16 LDS, biases/W3 -> LDS ----
    for (int e = tid; e < 4096; e += 1024) {
        int o = e >> 6, i = e & 63;
        w1s[o * 72 + i] = f2bf(W1[e]);
        w2s[o * 72 + i] = f2bf(W2[e]);
    }
    if (tid < 64) {
        bias1_s[tid] = b1[tid];
        bias2_s[tid] = b2[tid];
        w3_s[tid]    = W3[tid];
    }
    if (tid < 64) orow[c0 + tid] = grow[c0 + tid];

    for (int t = 1; t < NT; ++t) {
        // ---- wave0: refresh strip (halo exchange) + shock-proximity scan ----
        if (wid == 0) {
            if (t == 1) {
                int ga = c0 - 32 + lane;  ga = ga < 0 ? 0 : ga;
                int gb = c0 + 32 + lane;  gb = gb > NX - 1 ? NX - 1 : gb;
                st_s[lane]      = grow[ga];
                st_s[lane + 64] = grow[gb];
                asm volatile("s_waitcnt lgkmcnt(0)" ::: "memory");
            } else {
                const unsigned need = (unsigned)(t - 1);
                if (lane < 2) {           // lane0: left tag, lane1: right tag
                    bool has = lane ? (bb < NBPB - 1) : (bb > 0);
                    if (has) {
                        const unsigned* tp = &tags[bid + (lane ? 1 : -1)];
                        while (sys_load_u(tp) < need) __builtin_amdgcn_s_sleep(1);
                    }
                }
                const int p = (t - 1) & 1;
                const int j = lane & 31;
                if (lane < 32) {
                    float v = (bb > 0)
                        ? sys_load_f(&halo[(size_t)(bid - 1) * 128 + p * 64 + 32 + j])
                        : st_s[32];                 // clamp: global cell 0
                    st_s[j] = v;
                } else {
                    float v = (bb < NBPB - 1)
                        ? sys_load_f(&halo[(size_t)(bid + 1) * 128 + p * 64 + j])
                        : st_s[95];                 // clamp: global cell NX-1
                    st_s[96 + j] = v;
                }
            }

            // ---- strip prefix/suffix min scan -> prox ----
            const int j0 = 2 * lane, j1 = j0 + 1;
            const int g0 = c0 - 32 + j0, g1 = g0 + 1;
            float sjm1 = (j0 >= 1)  ? st_s[j0 - 1] : BIGF;
            float s0v  = st_s[j0];
            float s1v  = st_s[j1];
            float sp2  = (j1 < 127) ? st_s[j1 + 1] : -BIGF;
            float aL0 = (j0 >= 1 && s0v > sjm1) ? (0.5f - (float)g0) * DXC : BIGF;
            float aL1 = (s1v > s0v)             ? (0.5f - (float)g1) * DXC : BIGF;
            float aR0 = (s1v > s0v)             ? ((float)g0 + 0.5f) * DXC : BIGF;
            float aR1 = (j1 < 127 && sp2 > s1v) ? ((float)g1 + 0.5f) * DXC : BIGF;

            float m0 = aL0, m1 = fminf(aL0, aL1);
            float T = m1;
            #pragma unroll
            for (int off = 1; off < 64; off <<= 1) {
                float u = __shfl_up(T, off);
                if (lane >= off) T = fminf(T, u);
            }
            float ex = __shfl_up(T, 1); if (lane == 0) ex = BIGF;
            float p0 = fminf(ex, m0), p1 = fminf(ex, m1);
            float q1 = aR1, q0 = fminf(aR0, aR1);
            float S = q0;
            #pragma unroll
            for (int off = 1; off < 64; off <<= 1) {
                float u = __shfl_down(S, off);
                if (lane < 64 - off) S = fminf(S, u);
            }
            float sx = __shfl_down(S, 1); if (lane == 63) sx = BIGF;
            float sm0 = fminf(sx, q0), sm1 = fminf(sx, q1);

            float x0 = (float)g0 * DXC, x1 = (float)g1 * DXC;
            prox_s[j0] = __expf(-fminf(x0 + p0, sm0 - x0) * INV_SIG);
            prox_s[j1] = __expf(-fminf(x1 + p1, sm1 - x1) * INV_SIG);
        }
        __syncthreads();   // A: strip + prox ready (and prologue on t==1)

        // ---- L0 (fp32 VALU) -> actA bf16 ----
        {
            float f[22];
            #pragma unroll
            for (int k = 0; k < 7; ++k) {
                int ii = gi - 3 + k;
                ii = ii < 0 ? 0 : (ii > NX - 1 ? NX - 1 : ii);
                int si = ii - c0 + 32;
                float sv = st_s[si];
                f[k]      = sv;
                f[7 + k]  = 1.0f - 2.0f * sv;
                f[14 + k] = prox_s[si];
            }
            f[21] = dtv;

            const float* w = W0 + o0 * 22;
            float acc0 = b0[o0], acc1 = b0[o0 + 1], acc2 = b0[o0 + 2], acc3 = b0[o0 + 3];
            #pragma unroll
            for (int c = 0; c < 22; ++c) {
                float fv = f[c];
                acc0 += w[c]      * fv;
                acc1 += w[22 + c] * fv;
                acc2 += w[44 + c] * fv;
                acc3 += w[66 + c] * fv;
            }
            ushort4 pk;
            pk.x = f2bf(fast_gelu(acc0));
            pk.y = f2bf(fast_gelu(acc1));
            pk.z = f2bf(fast_gelu(acc2));
            pk.w = f2bf(fast_gelu(acc3));
            *reinterpret_cast<ushort4*>(&actA[cell * 72 + o0]) = pk;
        }
        __syncthreads();   // B: actA ready

        const int tm  = wid >> 2, tn = wid & 3;
        const int l15 = lane & 15;
        const int lk  = (lane >> 4) << 3;            // k-base within 32: 0,8,16,24
        const int col = tn * 16 + l15;
        const int row0 = tm * 16 + ((lane >> 4) << 2);

        // ---- L1 (MFMA bf16): actA x W1^T -> actB bf16 ----
        {
            f32x4 c = {0.0f, 0.0f, 0.0f, 0.0f};
            c = __builtin_amdgcn_mfma_f32_16x16x32_bf16(
                    *(const bf16x8*)(const void*)&actA[(tm * 16 + l15) * 72 + lk],
                    *(const bf16x8*)(const void*)&w1s[(tn * 16 + l15) * 72 + lk], c, 0, 0, 0);
            c = __builtin_amdgcn_mfma_f32_16x16x32_bf16(
                    *(const bf16x8*)(const void*)&actA[(tm * 16 + l15) * 72 + 32 + lk],
                    *(const bf16x8*)(const void*)&w1s[(tn * 16 + l15) * 72 + 32 + lk], c, 0, 0, 0);
            float bias = bias1_s[col];
            #pragma unroll
            for (int j = 0; j < 4; ++j) {
                actB[(row0 + j) * 72 + col] = f2bf(fast_gelu(c[j] + bias));
            }
        }
        __syncthreads();   // C: actB ready

        // ---- L2 (MFMA bf16) + fused L3 partial ----
        {
            f32x4 c = {0.0f, 0.0f, 0.0f, 0.0f};
            c = __builtin_amdgcn_mfma_f32_16x16x32_bf16(
                    *(const bf16x8*)(const void*)&actB[(tm * 16 + l15) * 72 + lk],
                    *(const bf16x8*)(const void*)&w2s[(tn * 16 + l15) * 72 + lk], c, 0, 0, 0);
            c = __builtin_amdgcn_mfma_f32_16x16x32_bf16(
                    *(const bf16x8*)(const void*)&actB[(tm * 16 + l15) * 72 + 32 + lk],
                    *(const bf16x8*)(const void*)&w2s[(tn * 16 + l15) * 72 + 32 + lk], c, 0, 0, 0);
            float bias = bias2_s[col];
            float w3c  = w3_s[col];
            #pragma unroll
            for (int j = 0; j < 4; ++j) {
                float p = w3c * fast_gelu(c[j] + bias);
                p += __shfl_xor(p, 1);
                p += __shfl_xor(p, 2);
                p += __shfl_xor(p, 4);
                p += __shfl_xor(p, 8);
                if (l15 == 0) part_s[(row0 + j) * 5 + tn] = p;
            }
        }
        __syncthreads();   // D: partials ready

        // ---- wave0: reduce + update + store + halo publish ----
        if (wid == 0) {
            float sum = part_s[lane * 5 + 0] + part_s[lane * 5 + 1]
                      + part_s[lane * 5 + 2] + part_s[lane * 5 + 3];
            float ns = st_s[lane + 32] + r * (sum + b3v);
            ns = fminf(1.0f, fmaxf(0.0f, ns));
            orow[(size_t)t * NX + gi] = ns;
            st_s[32 + lane] = ns;                  // keep own row resident in LDS
            if (t < NT - 1) {
                sys_store_f(&halo[(size_t)bid * 128 + (t & 1) * 64 + lane], ns);
                asm volatile("s_waitcnt vmcnt(0)" ::: "memory");  // halo visible before tag
                if (lane == 0) sys_store_u(&tags[bid], (unsigned)t);
            }
        }
        // next iter's sync A guards st_s/prox_s/actA/part_s reuse
    }
}

extern "C" void kernel_launch(void* const* d_in, const int* in_sizes, int n_in,
                              void* d_out, int out_size, void* d_ws, size_t ws_size,
                              hipStream_t stream) {
    const float* grid = (const float*)d_in[0];
    const float* dtp  = (const float*)d_in[1];
    const float* W0   = (const float*)d_in[2];
    const float* b0   = (const float*)d_in[3];
    const float* W1   = (const float*)d_in[4];
    const float* b1   = (const float*)d_in[5];
    const float* W2   = (const float*)d_in[6];
    const float* b2   = (const float*)d_in[7];
    const float* W3   = (const float*)d_in[8];
    const float* b3   = (const float*)d_in[9];
    float* outp = (float*)d_out;

    unsigned* tags = (unsigned*)d_ws;                       // NBLK u32
    float*    halo = (float*)((char*)d_ws + 1024);          // NBLK * 2 * 64 floats

    hipMemsetAsync(d_ws, 0, 1024, stream);   // zero tags each launch

    void* args[] = {(void*)&grid, (void*)&dtp, (void*)&W0, (void*)&b0,
                    (void*)&W1, (void*)&b1, (void*)&W2, (void*)&b2,
                    (void*)&W3, (void*)&b3, (void*)&outp, (void*)&tags, (void*)&halo};
    hipLaunchCooperativeKernel((const void*)nfv_kernel,
                               dim3(NBLK), dim3(1024), args, 0, stream);
}

// Round 7
// 317.543 us; speedup vs baseline: 8.3807x; 1.2983x over previous
//
#include <hip/hip_runtime.h>

#define NX 1024
#define NT 64
#define NBATCH 16
#define NBPB 16          // blocks per batch (64 cells each)
#define NBLK (NBATCH * NBPB)
#define DXC 0.02f
#define INV_SIG 20.0f
#define BIGF 1.0e6f

typedef __attribute__((ext_vector_type(8))) short bf16x8;
typedef __attribute__((ext_vector_type(4))) float f32x4;
typedef unsigned long long u64t;

// round-to-nearest-even f32 -> bf16
__device__ __forceinline__ unsigned short f2bf(float x) {
    unsigned u = __builtin_bit_cast(unsigned, x);
    u += 0x7FFFu + ((u >> 16) & 1u);
    return (unsigned short)(u >> 16);
}

// Exact-GELU via Abramowitz-Stegun 7.1.26 erf (|err| <= 1.5e-7).
__device__ __forceinline__ float fast_gelu(float x) {
    float z = fabsf(x) * 0.70710678118654752f;
    float t = __builtin_amdgcn_rcpf(fmaf(0.3275911f, z, 1.0f));
    float p = fmaf(t, 1.061405429f, -1.453152027f);
    p = fmaf(t, p, 1.421413741f);
    p = fmaf(t, p, -0.284496736f);
    p = fmaf(t, p, 0.254829592f);
    p = p * t;
    float e = __expf(-z * z);
    float erf_abs = fmaf(-p, e, 1.0f);
    return 0.5f * x * (1.0f + copysignf(erf_abs, x));
}

// SYSTEM-scope relaxed (L3 coherence point; no cache inv/wb) — cross-XCD safe.
// Proven live in rounds 4-5; used for ALL neighbor pairs (no XCD fast path).
__device__ __forceinline__ u64t sys_load_u64(const u64t* p) {
    return __hip_atomic_load(p, __ATOMIC_RELAXED, __HIP_MEMORY_SCOPE_SYSTEM);
}
__device__ __forceinline__ void sys_store_u64(u64t* p, u64t v) {
    __hip_atomic_store(p, v, __ATOMIC_RELAXED, __HIP_MEMORY_SCOPE_SYSTEM);
}

// XOR-swizzled [64][64] bf16 LDS layout: 16B chunk index XOR'd with row.
__device__ __forceinline__ int swz(int row, int k) {
    return (row << 6) + ((((k >> 3) ^ row) & 7) << 3) + (k & 7);
}

__global__ void __launch_bounds__(1024, 1) nfv_kernel(
    const float* __restrict__ grid, const float* __restrict__ dtp,
    const float* __restrict__ W0, const float* __restrict__ b0,
    const float* __restrict__ W1, const float* __restrict__ b1,
    const float* __restrict__ W2, const float* __restrict__ b2,
    const float* __restrict__ W3, const float* __restrict__ b3,
    float* __restrict__ outp, u64t* __restrict__ halo)
{
    __shared__ float st_s[128];     // state strip, global [c0-32, c0+96)
    __shared__ float prox_s[128];
    __shared__ __align__(16) unsigned short actA[64 * 64];
    __shared__ __align__(16) unsigned short actB[64 * 64];
    __shared__ __align__(16) unsigned short w1s[64 * 64];
    __shared__ __align__(16) unsigned short w2s[64 * 64];
    __shared__ float bias1_s[64], bias2_s[64], w3_s[64];
    __shared__ float part_s[64 * 5];

    const int tid  = threadIdx.x;
    const int lane = tid & 63;
    const int wid  = tid >> 6;
    const int bid  = blockIdx.x;
    const int b    = bid >> 4;            // batch
    const int bb   = bid & 15;            // block within batch
    const int cell = lane;
    const int c0   = bb * 64;
    const int gi   = c0 + cell;
    const float dtv = dtp[b];
    const float r   = dtv / DXC;
    const float b3v = b3[0];
    const int o0   = __builtin_amdgcn_readfirstlane(wid * 4);

    const float* grow = grid + (size_t)b * (NT * NX);
    float*       orow = outp + (size_t)b * (NT * NX);

    // ---- prologue: weights -> swizzled bf16 LDS ----
    for (int e = tid; e < 4096; e += 1024) {
        int o = e >> 6, i = e & 63;
        w1s[swz(o, i)] = f2bf(W1[e]);
        w2s[swz(o, i)] = f2bf(W2[e]);
    }
    if (tid < 64) {
        bias1_s[tid] = b1[tid];
        bias2_s[tid] = b2[tid];
        w3_s[tid]    = W3[tid];
        orow[c0 + tid] = grow[c0 + tid];   // t = 0 output
    }

    for (int t = 1; t < NT; ++t) {
        // ---- wave0: fill strip halo (single-RT fused data+tag poll) ----
        if (wid == 0) {
            if (t == 1) {
                int ga = c0 - 32 + lane;  ga = ga < 0 ? 0 : ga;
                int gb = c0 + 32 + lane;  gb = gb > NX - 1 ? NX - 1 : gb;
                st_s[lane]      = grow[ga];
                st_s[lane + 64] = grow[gb];
            } else {
                const unsigned need = (unsigned)(t - 1);
                const int p = (t - 1) & 1;
                const int j = lane & 31;
                const bool left = lane < 32;
                const bool have = left ? (bb > 0) : (bb < NBPB - 1);
                float v;
                if (have) {
                    const u64t* src = left
                        ? &halo[(size_t)(bid - 1) * 128 + p * 64 + 32 + j]
                        : &halo[(size_t)(bid + 1) * 128 + p * 64 + j];
                    u64t u;
                    do { u = sys_load_u64(src); } while ((unsigned)(u >> 32) < need);
                    v = __builtin_bit_cast(float, (unsigned)u);
                } else {
                    v = left ? st_s[32] : st_s[95];   // edge clamp (own prev row)
                }
                st_s[left ? j : 96 + j] = v;
            }
        }
        __syncthreads();   // A: strip ready (and prologue staging on t==1)

        // ---- ALL waves: duplicated strip scan -> prox (identical writes) ----
        {
            const int j0 = 2 * lane, j1 = j0 + 1;
            const int g0 = c0 - 32 + j0, g1 = g0 + 1;
            float sjm1 = (j0 >= 1)  ? st_s[j0 - 1] : BIGF;
            float s0v  = st_s[j0];
            float s1v  = st_s[j1];
            float sp2  = (j1 < 127) ? st_s[j1 + 1] : -BIGF;
            float aL0 = (j0 >= 1 && s0v > sjm1) ? (0.5f - (float)g0) * DXC : BIGF;
            float aL1 = (s1v > s0v)             ? (0.5f - (float)g1) * DXC : BIGF;
            float aR0 = (s1v > s0v)             ? ((float)g0 + 0.5f) * DXC : BIGF;
            float aR1 = (j1 < 127 && sp2 > s1v) ? ((float)g1 + 0.5f) * DXC : BIGF;

            float m0 = aL0, m1 = fminf(aL0, aL1);
            float T = m1;
            #pragma unroll
            for (int off = 1; off < 64; off <<= 1) {
                float u = __shfl_up(T, off);
                if (lane >= off) T = fminf(T, u);
            }
            float ex = __shfl_up(T, 1); if (lane == 0) ex = BIGF;
            float p0 = fminf(ex, m0), p1 = fminf(ex, m1);
            float q1 = aR1, q0 = fminf(aR0, aR1);
            float S = q0;
            #pragma unroll
            for (int off = 1; off < 64; off <<= 1) {
                float u = __shfl_down(S, off);
                if (lane < 64 - off) S = fminf(S, u);
            }
            float sx = __shfl_down(S, 1); if (lane == 63) sx = BIGF;
            float sm0 = fminf(sx, q0), sm1 = fminf(sx, q1);

            float x0 = (float)g0 * DXC, x1 = (float)g1 * DXC;
            prox_s[j0] = __expf(-fminf(x0 + p0, sm0 - x0) * INV_SIG);
            prox_s[j1] = __expf(-fminf(x1 + p1, sm1 - x1) * INV_SIG);
        }

        // ---- L0 (fp32 VALU) -> actA bf16 (swizzled) ----
        {
            float f[22];
            #pragma unroll
            for (int k = 0; k < 7; ++k) {
                int ii = gi - 3 + k;
                ii = ii < 0 ? 0 : (ii > NX - 1 ? NX - 1 : ii);
                int si = ii - c0 + 32;
                float sv = st_s[si];
                f[k]      = sv;
                f[7 + k]  = 1.0f - 2.0f * sv;
                f[14 + k] = prox_s[si];
            }
            f[21] = dtv;

            const float* w = W0 + o0 * 22;
            float acc0 = b0[o0], acc1 = b0[o0 + 1], acc2 = b0[o0 + 2], acc3 = b0[o0 + 3];
            #pragma unroll
            for (int c = 0; c < 22; ++c) {
                float fv = f[c];
                acc0 += w[c]      * fv;
                acc1 += w[22 + c] * fv;
                acc2 += w[44 + c] * fv;
                acc3 += w[66 + c] * fv;
            }
            ushort4 pk;
            pk.x = f2bf(fast_gelu(acc0));
            pk.y = f2bf(fast_gelu(acc1));
            pk.z = f2bf(fast_gelu(acc2));
            pk.w = f2bf(fast_gelu(acc3));
            *reinterpret_cast<ushort4*>(&actA[swz(cell, o0)]) = pk;   // 8B aligned (o0%4==0)
        }
        __syncthreads();   // B: actA ready

        const int tm  = wid >> 2, tn = wid & 3;
        const int l15 = lane & 15;
        const int kb0 = lane >> 4;                   // 16B-chunk idx in 64-k row: 0..3
        const int col = tn * 16 + l15;
        const int row0 = tm * 16 + ((lane >> 4) << 2);
        const int arow = tm * 16 + l15;
        const int brow = tn * 16 + l15;

        // ---- L1 (MFMA bf16): actA x W1^T -> actB (swizzled) ----
        {
            f32x4 c = {0.0f, 0.0f, 0.0f, 0.0f};
            c = __builtin_amdgcn_mfma_f32_16x16x32_bf16(
                    *(const bf16x8*)(const void*)&actA[(arow << 6) + (((kb0     ^ arow) & 7) << 3)],
                    *(const bf16x8*)(const void*)&w1s [(brow << 6) + (((kb0     ^ brow) & 7) << 3)], c, 0, 0, 0);
            c = __builtin_amdgcn_mfma_f32_16x16x32_bf16(
                    *(const bf16x8*)(const void*)&actA[(arow << 6) + ((((kb0+4) ^ arow) & 7) << 3)],
                    *(const bf16x8*)(const void*)&w1s [(brow << 6) + ((((kb0+4) ^ brow) & 7) << 3)], c, 0, 0, 0);
            float bias = bias1_s[col];
            #pragma unroll
            for (int j = 0; j < 4; ++j) {
                actB[swz(row0 + j, col)] = f2bf(fast_gelu(c[j] + bias));
            }
        }
        __syncthreads();   // C: actB ready

        // ---- L2 (MFMA bf16) + fused L3 partial ----
        {
            f32x4 c = {0.0f, 0.0f, 0.0f, 0.0f};
            c = __builtin_amdgcn_mfma_f32_16x16x32_bf16(
                    *(const bf16x8*)(const void*)&actB[(arow << 6) + (((kb0     ^ arow) & 7) << 3)],
                    *(const bf16x8*)(const void*)&w2s [(brow << 6) + (((kb0     ^ brow) & 7) << 3)], c, 0, 0, 0);
            c = __builtin_amdgcn_mfma_f32_16x16x32_bf16(
                    *(const bf16x8*)(const void*)&actB[(arow << 6) + ((((kb0+4) ^ arow) & 7) << 3)],
                    *(const bf16x8*)(const void*)&w2s [(brow << 6) + ((((kb0+4) ^ brow) & 7) << 3)], c, 0, 0, 0);
            float bias = bias2_s[col];
            float w3c  = w3_s[col];
            #pragma unroll
            for (int j = 0; j < 4; ++j) {
                float p = w3c * fast_gelu(c[j] + bias);
                p += __shfl_xor(p, 1);
                p += __shfl_xor(p, 2);
                p += __shfl_xor(p, 4);
                p += __shfl_xor(p, 8);
                if (l15 == 0) part_s[(row0 + j) * 5 + tn] = p;
            }
        }
        __syncthreads();   // D: partials ready

        // ---- wave0: reduce + update + publish (halo first) + store ----
        if (wid == 0) {
            float sum = part_s[lane * 5 + 0] + part_s[lane * 5 + 1]
                      + part_s[lane * 5 + 2] + part_s[lane * 5 + 3];
            float ns = st_s[lane + 32] + r * (sum + b3v);
            ns = fminf(1.0f, fmaxf(0.0f, ns));
            if (t < NT - 1) {
                u64t u = ((u64t)(unsigned)t << 32) |
                         (u64t)(unsigned)__builtin_bit_cast(unsigned, ns);
                sys_store_u64(&halo[(size_t)bid * 128 + (t & 1) * 64 + lane], u);
            }
            st_s[32 + lane] = ns;                  // keep own row resident in LDS
            orow[(size_t)t * NX + gi] = ns;
        }
        // next iter's barrier A guards st_s/prox_s/actA/part_s reuse
    }
}

extern "C" void kernel_launch(void* const* d_in, const int* in_sizes, int n_in,
                              void* d_out, int out_size, void* d_ws, size_t ws_size,
                              hipStream_t stream) {
    const float* grid = (const float*)d_in[0];
    const float* dtp  = (const float*)d_in[1];
    const float* W0   = (const float*)d_in[2];
    const float* b0   = (const float*)d_in[3];
    const float* W1   = (const float*)d_in[4];
    const float* b1   = (const float*)d_in[5];
    const float* W2   = (const float*)d_in[6];
    const float* b2   = (const float*)d_in[7];
    const float* W3   = (const float*)d_in[8];
    const float* b3   = (const float*)d_in[9];
    float* outp = (float*)d_out;

    u64t* halo = (u64t*)d_ws;                     // NBLK * 128 u64 (256 KB)

    // zero the whole halo each launch: tags embedded in data words must not
    // leak across graph replays (stale tag >= need would hand out old rows)
    hipMemsetAsync(d_ws, 0, (size_t)NBLK * 128 * sizeof(u64t), stream);

    void* args[] = {(void*)&grid, (void*)&dtp, (void*)&W0, (void*)&b0,
                    (void*)&W1, (void*)&b1, (void*)&W2, (void*)&b2,
                    (void*)&W3, (void*)&b3, (void*)&outp, (void*)&halo};
    hipLaunchCooperativeKernel((const void*)nfv_kernel,
                               dim3(NBLK), dim3(1024), args, 0, stream);
}

// Round 9
// 269.180 us; speedup vs baseline: 9.8865x; 1.1797x over previous
//
#include <hip/hip_runtime.h>

#define NX 1024
#define NT 64
#define NBATCH 16
#define NBPB 16          // blocks per batch (64 cells each)
#define NBLK (NBATCH * NBPB)
#define DXC 0.02f
#define INV_SIG 20.0f
#define BIGF 1.0e6f

typedef __attribute__((ext_vector_type(8))) short bf16x8;
typedef __attribute__((ext_vector_type(4))) float f32x4;
typedef unsigned long long u64t;

// round-to-nearest-even f32 -> bf16
__device__ __forceinline__ unsigned short f2bf(float x) {
    unsigned u = __builtin_bit_cast(unsigned, x);
    u += 0x7FFFu + ((u >> 16) & 1u);
    return (unsigned short)(u >> 16);
}
__device__ __forceinline__ float bf2f(unsigned short h) {
    return __builtin_bit_cast(float, (unsigned)h << 16);
}

// Exact-GELU via Abramowitz-Stegun 7.1.26 erf (|err| <= 1.5e-7).
__device__ __forceinline__ float fast_gelu(float x) {
    float z = fabsf(x) * 0.70710678118654752f;
    float t = __builtin_amdgcn_rcpf(fmaf(0.3275911f, z, 1.0f));
    float p = fmaf(t, 1.061405429f, -1.453152027f);
    p = fmaf(t, p, 1.421413741f);
    p = fmaf(t, p, -0.284496736f);
    p = fmaf(t, p, 0.254829592f);
    p = p * t;
    float e = __expf(-z * z);
    float erf_abs = fmaf(-p, e, 1.0f);
    return 0.5f * x * (1.0f + copysignf(erf_abs, x));
}

// SYSTEM-scope relaxed (L3 coherence point; no cache inv/wb) — cross-XCD safe.
__device__ __forceinline__ u64t sys_load_u64(const u64t* p) {
    return __hip_atomic_load(p, __ATOMIC_RELAXED, __HIP_MEMORY_SCOPE_SYSTEM);
}
__device__ __forceinline__ void sys_store_u64(u64t* p, u64t v) {
    __hip_atomic_store(p, v, __ATOMIC_RELAXED, __HIP_MEMORY_SCOPE_SYSTEM);
}

// XOR-swizzled [64][64] bf16 LDS layout: 16B chunk index XOR'd with row.
__device__ __forceinline__ int swz(int row, int k) {
    return (row << 6) + ((((k >> 3) ^ row) & 7) << 3) + (k & 7);
}
// XOR-swizzled [64][32] bf16 layout (4 chunks/row) for features / W0.
__device__ __forceinline__ int swz4(int row, int k) {
    return (row << 5) + ((((k >> 3) ^ row) & 3) << 3) + (k & 7);
}

__global__ void __launch_bounds__(1024, 1) nfv_kernel(
    const float* __restrict__ grid, const float* __restrict__ dtp,
    const float* __restrict__ W0, const float* __restrict__ b0,
    const float* __restrict__ W1, const float* __restrict__ b1,
    const float* __restrict__ W2, const float* __restrict__ b2,
    const float* __restrict__ W3, const float* __restrict__ b3,
    float* __restrict__ outp, u64t* __restrict__ halo)
{
    __shared__ float st_s[128];     // state strip, global [c0-32, c0+96)
    __shared__ __align__(16) unsigned short feat_s[64 * 32]; // bf16 features
    __shared__ __align__(16) unsigned short w0s[64 * 32];    // bf16 W0' padded
    __shared__ __align__(16) unsigned short actA[64 * 64];
    __shared__ __align__(16) unsigned short actB[64 * 64];
    __shared__ __align__(16) unsigned short w1s[64 * 64];
    __shared__ __align__(16) unsigned short w2s[64 * 64];
    __shared__ float bias0_s[64], bias1_s[64], bias2_s[64], w3_s[64];
    __shared__ float part_s[64 * 5];

    const int tid  = threadIdx.x;
    const int lane = tid & 63;
    const int wid  = tid >> 6;
    const int bid  = blockIdx.x;
    const int b    = bid >> 4;            // batch
    const int bb   = bid & 15;            // block within batch
    const int c0   = bb * 64;
    const int gi   = c0 + lane;
    const float dtv = dtp[b];
    const float r   = dtv / DXC;
    const float b3v = b3[0];

    const float* grow = grid + (size_t)b * (NT * NX);
    float*       orow = outp + (size_t)b * (NT * NX);

    // ---- prologue: weights -> swizzled bf16 LDS ----
    for (int e = tid; e < 4096; e += 1024) {
        int o = e >> 6, i = e & 63;
        w1s[swz(o, i)] = f2bf(W1[e]);
        w2s[swz(o, i)] = f2bf(W2[e]);
    }
    // L0 refactor: W0[:,k]*s + W0[:,7+k]*(1-2s) = A_k*s + W0[:,7+k],
    //   A_k = W0[:,k] - 2*W0[:,7+k].  Slot k: A_k (s_hi), slot 7+k: A_k (s_lo),
    //   slots 14..20: prox weights, 21: dt weight, 22..31: zero pad.
    for (int e = tid; e < 2048; e += 1024) {
        int o = e >> 5, i = e & 31;
        float wv;
        if (i < 7)       wv = W0[o * 22 + i] - 2.0f * W0[o * 22 + 7 + i];
        else if (i < 14) wv = W0[o * 22 + (i - 7)] - 2.0f * W0[o * 22 + i];
        else if (i < 22) wv = W0[o * 22 + i];
        else             wv = 0.0f;
        w0s[swz4(o, i)] = f2bf(wv);
    }
    ((unsigned*)feat_s)[tid] = 0;      // zero all entries (pad K stays 0)
    if (tid < 64) {
        float bb0 = b0[tid];
        #pragma unroll
        for (int k = 7; k < 14; ++k) bb0 += W0[tid * 22 + k];  // char constant fold
        bias0_s[tid] = bb0;
        bias1_s[tid] = b1[tid];
        bias2_s[tid] = b2[tid];
        w3_s[tid]    = W3[tid];
        orow[c0 + tid] = grow[c0 + tid];   // t = 0 output
    }

    // fragment geometry (shared by L0/L1/L2)
    const int tm  = wid >> 2, tn = wid & 3;
    const int l15 = lane & 15;
    const int kb0 = lane >> 4;                   // 16B-chunk idx: 0..3
    const int col = tn * 16 + l15;
    const int row0 = tm * 16 + ((lane >> 4) << 2);
    const int arow = tm * 16 + l15;
    const int brow = tn * 16 + l15;

    for (int t = 1; t < NT; ++t) {
        // ---- wave0: fill strip halo (single-RT fused data+tag poll) ----
        if (wid == 0) {
            if (t == 1) {
                int ga = c0 - 32 + lane;  ga = ga < 0 ? 0 : ga;
                int gb = c0 + 32 + lane;  gb = gb > NX - 1 ? NX - 1 : gb;
                st_s[lane]      = grow[ga];
                st_s[lane + 64] = grow[gb];
            } else {
                const unsigned need = (unsigned)(t - 1);
                const int p = (t - 1) & 1;
                const int j = lane & 31;
                const bool left = lane < 32;
                const bool have = left ? (bb > 0) : (bb < NBPB - 1);
                float v;
                if (have) {
                    const u64t* src = left
                        ? &halo[(size_t)(bid - 1) * 128 + p * 64 + 32 + j]
                        : &halo[(size_t)(bid + 1) * 128 + p * 64 + j];
                    u64t u;
                    do { u = sys_load_u64(src); } while ((unsigned)(u >> 32) < need);
                    v = __builtin_bit_cast(float, (unsigned)u);
                } else {
                    v = left ? st_s[32] : st_s[95];   // edge clamp (own prev row)
                }
                st_s[left ? j : 96 + j] = v;
            }
        }
        __syncthreads();   // A: strip ready

        // ---- waves 0-7: ballot prox + feature build -> feat_s ----
        if (wid < 7) {
            // shock ballots over strip pairs p=0..126 (pair p: cells p,p+1)
            bool p0 = st_s[lane + 1] > st_s[lane];
            int i2 = 65 + lane; if (i2 > 127) i2 = 127;
            bool p1 = (lane < 63) && (st_s[i2] > st_s[64 + lane]);
            u64t m0 = __ballot(p0);
            u64t m1 = __ballot(p1);

            // query cell: strip idx of stencil slot wid for row `lane`,
            // CLAMPED at batch-row edges (reference pads with mode='edge')
            int c = lane + 29 + wid;
            if (bb == 0      && c < 32) c = 32;
            if (bb == NBPB-1 && c > 95) c = 95;

            float dL = BIGF, dR = BIGF;
            // LEFT: highest pair p <= c-1
            u64t selhi = 0, sello;
            if (c >= 65) selhi = m1 & (((u64t)1 << (c - 64)) - 1);
            sello = (c <= 63) ? (m0 & (((u64t)1 << c) - 1)) : m0;
            if (selhi)      dL = (float)(c - (127 - __builtin_clzll(selhi))) - 0.5f;
            else if (sello) dL = (float)(c - (63  - __builtin_clzll(sello))) - 0.5f;
            // RIGHT: lowest pair p >= c
            if (c <= 63) {
                u64t r0 = m0 >> c;
                if (r0)      dR = (float)__builtin_ctzll(r0) + 0.5f;
                else if (m1) dR = (float)(64 - c + __builtin_ctzll(m1)) + 0.5f;
            } else {
                u64t r1 = m1 >> (c - 64);
                if (r1)      dR = (float)__builtin_ctzll(r1) + 0.5f;
            }
            float d = fminf(dL, dR);                    // in cell units
            float prox = __expf(-d * (DXC * INV_SIG));

            float sv = st_s[c];
            unsigned short shi = f2bf(sv);
            unsigned short slo = f2bf(sv - bf2f(shi));  // double-bf16 state
            feat_s[swz4(lane, wid)]      = shi;
            feat_s[swz4(lane, 7 + wid)]  = slo;
            feat_s[swz4(lane, 14 + wid)] = f2bf(prox);
        } else if (wid == 7) {
            feat_s[swz4(lane, 21)] = f2bf(dtv);
        }
        __syncthreads();   // B: features ready

        // ---- L0 (1x MFMA bf16, K=32): feat x W0'^T -> actA ----
        {
            f32x4 c4 = {0.0f, 0.0f, 0.0f, 0.0f};
            c4 = __builtin_amdgcn_mfma_f32_16x16x32_bf16(
                    *(const bf16x8*)(const void*)&feat_s[(arow << 5) + (((kb0 ^ arow) & 3) << 3)],
                    *(const bf16x8*)(const void*)&w0s   [(brow << 5) + (((kb0 ^ brow) & 3) << 3)], c4, 0, 0, 0);
            float bias = bias0_s[col];
            #pragma unroll
            for (int j = 0; j < 4; ++j) {
                actA[swz(row0 + j, col)] = f2bf(fast_gelu(c4[j] + bias));
            }
        }
        __syncthreads();   // C: actA ready

        // ---- L1 (MFMA bf16): actA x W1^T -> actB ----
        {
            f32x4 c4 = {0.0f, 0.0f, 0.0f, 0.0f};
            c4 = __builtin_amdgcn_mfma_f32_16x16x32_bf16(
                    *(const bf16x8*)(const void*)&actA[(arow << 6) + (((kb0     ^ arow) & 7) << 3)],
                    *(const bf16x8*)(const void*)&w1s [(brow << 6) + (((kb0     ^ brow) & 7) << 3)], c4, 0, 0, 0);
            c4 = __builtin_amdgcn_mfma_f32_16x16x32_bf16(
                    *(const bf16x8*)(const void*)&actA[(arow << 6) + ((((kb0+4) ^ arow) & 7) << 3)],
                    *(const bf16x8*)(const void*)&w1s [(brow << 6) + ((((kb0+4) ^ brow) & 7) << 3)], c4, 0, 0, 0);
            float bias = bias1_s[col];
            #pragma unroll
            for (int j = 0; j < 4; ++j) {
                actB[swz(row0 + j, col)] = f2bf(fast_gelu(c4[j] + bias));
            }
        }
        __syncthreads();   // D: actB ready

        // ---- L2 (MFMA bf16) + fused L3 partial ----
        {
            f32x4 c4 = {0.0f, 0.0f, 0.0f, 0.0f};
            c4 = __builtin_amdgcn_mfma_f32_16x16x32_bf16(
                    *(const bf16x8*)(const void*)&actB[(arow << 6) + (((kb0     ^ arow) & 7) << 3)],
                    *(const bf16x8*)(const void*)&w2s [(brow << 6) + (((kb0     ^ brow) & 7) << 3)], c4, 0, 0, 0);
            c4 = __builtin_amdgcn_mfma_f32_16x16x32_bf16(
                    *(const bf16x8*)(const void*)&actB[(arow << 6) + ((((kb0+4) ^ arow) & 7) << 3)],
                    *(const bf16x8*)(const void*)&w2s [(brow << 6) + ((((kb0+4) ^ brow) & 7) << 3)], c4, 0, 0, 0);
            float bias = bias2_s[col];
            float w3c  = w3_s[col];
            #pragma unroll
            for (int j = 0; j < 4; ++j) {
                float p = w3c * fast_gelu(c4[j] + bias);
                p += __shfl_xor(p, 1);
                p += __shfl_xor(p, 2);
                p += __shfl_xor(p, 4);
                p += __shfl_xor(p, 8);
                if (l15 == 0) part_s[(row0 + j) * 5 + tn] = p;
            }
        }
        __syncthreads();   // E: partials ready

        // ---- wave0: reduce + update + publish (halo first) + store ----
        if (wid == 0) {
            float sum = part_s[lane * 5 + 0] + part_s[lane * 5 + 1]
                      + part_s[lane * 5 + 2] + part_s[lane * 5 + 3];
            float ns = st_s[lane + 32] + r * (sum + b3v);
            ns = fminf(1.0f, fmaxf(0.0f, ns));
            if (t < NT - 1) {
                u64t u = ((u64t)(unsigned)t << 32) |
                         (u64t)(unsigned)__builtin_bit_cast(unsigned, ns);
                sys_store_u64(&halo[(size_t)bid * 128 + (t & 1) * 64 + lane], u);
            }
            st_s[32 + lane] = ns;                  // keep own row resident in LDS
            orow[(size_t)t * NX + gi] = ns;
        }
        // next iter's barrier A guards st_s/feat_s/actA/part_s reuse
    }
}

extern "C" void kernel_launch(void* const* d_in, const int* in_sizes, int n_in,
                              void* d_out, int out_size, void* d_ws, size_t ws_size,
                              hipStream_t stream) {
    const float* grid = (const float*)d_in[0];
    const float* dtp  = (const float*)d_in[1];
    const float* W0   = (const float*)d_in[2];
    const float* b0   = (const float*)d_in[3];
    const float* W1   = (const float*)d_in[4];
    const float* b1   = (const float*)d_in[5];
    const float* W2   = (const float*)d_in[6];
    const float* b2   = (const float*)d_in[7];
    const float* W3   = (const float*)d_in[8];
    const float* b3   = (const float*)d_in[9];
    float* outp = (float*)d_out;

    u64t* halo = (u64t*)d_ws;                     // NBLK * 128 u64 (256 KB)

    // zero the whole halo each launch: tags embedded in data words must not
    // leak across graph replays (stale tag >= need would hand out old rows)
    hipMemsetAsync(d_ws, 0, (size_t)NBLK * 128 * sizeof(u64t), stream);

    void* args[] = {(void*)&grid, (void*)&dtp, (void*)&W0, (void*)&b0,
                    (void*)&W1, (void*)&b1, (void*)&W2, (void*)&b2,
                    (void*)&W3, (void*)&b3, (void*)&outp, (void*)&halo};
    hipLaunchCooperativeKernel((const void*)nfv_kernel,
                               dim3(NBLK), dim3(1024), args, 0, stream);
}

// Round 10
// 256.189 us; speedup vs baseline: 10.3878x; 1.0507x over previous
//
#include <hip/hip_runtime.h>

#define NX 1024
#define NT 64
#define NBATCH 16
#define NBPB 16          // blocks per batch (64 cells each)
#define NBLK (NBATCH * NBPB)
#define DXC 0.02f
#define INV_SIG 20.0f
#define BIGF 1.0e6f

typedef __attribute__((ext_vector_type(8))) short bf16x8;
typedef __attribute__((ext_vector_type(4))) float f32x4;
typedef unsigned long long u64t;

// round-to-nearest-even f32 -> bf16 (manual; used on non-hot paths)
__device__ __forceinline__ unsigned short f2bf(float x) {
    unsigned u = __builtin_bit_cast(unsigned, x);
    u += 0x7FFFu + ((u >> 16) & 1u);
    return (unsigned short)(u >> 16);
}
__device__ __forceinline__ float bf2f(unsigned short h) {
    return __builtin_bit_cast(float, (unsigned)h << 16);
}
// HW packed f32x2 -> bf16x2 (lo = src0, hi = src1)
__device__ __forceinline__ unsigned cvt_pk_bf16(float lo, float hi) {
    unsigned r;
    asm("v_cvt_pk_bf16_f32 %0, %1, %2" : "=v"(r) : "v"(lo), "v"(hi));
    return r;
}

// Exact-GELU via Abramowitz-Stegun 7.1.26 erf (|err| <= 1.5e-7).
__device__ __forceinline__ float fast_gelu(float x) {
    float z = fabsf(x) * 0.70710678118654752f;
    float t = __builtin_amdgcn_rcpf(fmaf(0.3275911f, z, 1.0f));
    float p = fmaf(t, 1.061405429f, -1.453152027f);
    p = fmaf(t, p, 1.421413741f);
    p = fmaf(t, p, -0.284496736f);
    p = fmaf(t, p, 0.254829592f);
    p = p * t;
    float e = __expf(-z * z);
    float erf_abs = fmaf(-p, e, 1.0f);
    return 0.5f * x * (1.0f + copysignf(erf_abs, x));
}

// SYSTEM-scope relaxed (L3 coherence point; no cache inv/wb) — cross-XCD safe.
__device__ __forceinline__ u64t sys_load_u64(const u64t* p) {
    return __hip_atomic_load(p, __ATOMIC_RELAXED, __HIP_MEMORY_SCOPE_SYSTEM);
}
__device__ __forceinline__ void sys_store_u64(u64t* p, u64t v) {
    __hip_atomic_store(p, v, __ATOMIC_RELAXED, __HIP_MEMORY_SCOPE_SYSTEM);
}

// XOR-swizzled [64][64] bf16 LDS layout: 16B chunk index XOR'd with row&7.
__device__ __forceinline__ int swz(int row, int k) {
    return (row << 6) + ((((k >> 3) ^ row) & 7) << 3) + (k & 7);
}

__global__ void __launch_bounds__(1024, 1) nfv_kernel(
    const float* __restrict__ grid, const float* __restrict__ dtp,
    const float* __restrict__ W0, const float* __restrict__ b0,
    const float* __restrict__ W1, const float* __restrict__ b1,
    const float* __restrict__ W2, const float* __restrict__ b2,
    const float* __restrict__ W3, const float* __restrict__ b3,
    float* __restrict__ outp, u64t* __restrict__ halo)
{
    __shared__ float st_s[128];     // state strip, global [c0-32, c0+96)
    __shared__ __align__(16) unsigned short feat_s[64 * 64]; // bf16 features, swz
    __shared__ __align__(16) unsigned short w0s[64 * 64];    // bf16 W0' (K<32), swz
    __shared__ __align__(16) unsigned short actA[64 * 64];
    __shared__ __align__(16) unsigned short actB[64 * 64];
    __shared__ __align__(16) unsigned short w1s[64 * 64];
    __shared__ __align__(16) unsigned short w2s[64 * 64];
    __shared__ float bias0_s[64], bias1_s[64], bias2_s[64], w3_s[64];
    __shared__ __align__(16) float part_s[64 * 20];          // L3 partials [row][16+pad]

    const int tid  = threadIdx.x;
    const int lane = tid & 63;
    const int wid  = tid >> 6;
    const int bid  = blockIdx.x;
    const int b    = bid >> 4;            // batch
    const int bb   = bid & 15;            // block within batch
    const int c0   = bb * 64;
    const int gi   = c0 + lane;
    const float dtv = dtp[b];
    const float r   = dtv / DXC;
    const float b3v = b3[0];

    const float* grow = grid + (size_t)b * (NT * NX);
    float*       orow = outp + (size_t)b * (NT * NX);

    // ---- prologue: weights -> swizzled bf16 LDS ----
    for (int e = tid; e < 4096; e += 1024) {
        int o = e >> 6, i = e & 63;
        w1s[swz(o, i)] = f2bf(W1[e]);
        w2s[swz(o, i)] = f2bf(W2[e]);
    }
    // L0 refactor: W0[:,k]*s + W0[:,7+k]*(1-2s) = A_k*s + W0[:,7+k],
    //   A_k = W0[:,k] - 2*W0[:,7+k].  Slot k: A_k (s_hi), slot 7+k: A_k (s_lo),
    //   slots 14..20: prox weights, 21: dt weight, 22..31: zero pad.
    for (int e = tid; e < 2048; e += 1024) {
        int o = e >> 5, i = e & 31;
        float wv;
        if (i < 7)       wv = W0[o * 22 + i] - 2.0f * W0[o * 22 + 7 + i];
        else if (i < 14) wv = W0[o * 22 + (i - 7)] - 2.0f * W0[o * 22 + i];
        else if (i < 22) wv = W0[o * 22 + i];
        else             wv = 0.0f;
        w0s[swz(o, i)] = f2bf(wv);
    }
    ((unsigned*)feat_s)[tid]        = 0;   // zero all 4096 bf16 entries
    ((unsigned*)feat_s)[tid + 1024] = 0;   // (pad K slots stay 0 forever)
    if (tid < 64) {
        float bb0 = b0[tid];
        #pragma unroll
        for (int k = 7; k < 14; ++k) bb0 += W0[tid * 22 + k];  // char constant fold
        bias0_s[tid] = bb0;
        bias1_s[tid] = b1[tid];
        bias2_s[tid] = b2[tid];
        w3_s[tid]    = W3[tid];
        orow[c0 + tid] = grow[c0 + tid];   // t = 0 output
    }

    // fragment geometry (shared by L0/L1/L2)
    const int tm  = wid >> 2, tn = wid & 3;
    const int l15 = lane & 15;
    const int kb0 = lane >> 4;                   // 16B-chunk idx: 0..3
    const int col = tn * 16 + l15;
    const int row0 = tm * 16 + ((lane >> 4) << 2);
    const int arow = tm * 16 + l15;
    const int brow = tn * 16 + l15;

    for (int t = 1; t < NT; ++t) {
        // ---- wave0: fill strip halo (single-RT fused data+tag poll) ----
        if (wid == 0) {
            if (t == 1) {
                int ga = c0 - 32 + lane;  ga = ga < 0 ? 0 : ga;
                int gb = c0 + 32 + lane;  gb = gb > NX - 1 ? NX - 1 : gb;
                st_s[lane]      = grow[ga];
                st_s[lane + 64] = grow[gb];
            } else {
                const unsigned need = (unsigned)(t - 1);
                const int p = (t - 1) & 1;
                const int j = lane & 31;
                const bool left = lane < 32;
                const bool have = left ? (bb > 0) : (bb < NBPB - 1);
                float v;
                if (have) {
                    const u64t* src = left
                        ? &halo[(size_t)(bid - 1) * 128 + p * 64 + 32 + j]
                        : &halo[(size_t)(bid + 1) * 128 + p * 64 + j];
                    u64t u;
                    do { u = sys_load_u64(src); } while ((unsigned)(u >> 32) < need);
                    v = __builtin_bit_cast(float, (unsigned)u);
                } else {
                    v = left ? st_s[32] : st_s[95];   // edge clamp (own prev row)
                }
                st_s[left ? j : 96 + j] = v;
            }
        }
        __syncthreads();   // A: strip ready

        // ---- waves 0-7: ballot prox + feature build -> feat_s ----
        if (wid < 7) {
            // shock ballots over strip pairs p=0..126 (pair p: cells p,p+1)
            bool p0 = st_s[lane + 1] > st_s[lane];
            int i2 = 65 + lane; if (i2 > 127) i2 = 127;
            bool p1 = (lane < 63) && (st_s[i2] > st_s[64 + lane]);
            u64t m0 = __ballot(p0);
            u64t m1 = __ballot(p1);

            // query cell: strip idx of stencil slot wid for row `lane`,
            // CLAMPED at batch-row edges (reference pads with mode='edge')
            int c = lane + 29 + wid;
            if (bb == 0      && c < 32) c = 32;
            if (bb == NBPB-1 && c > 95) c = 95;

            float dL = BIGF, dR = BIGF;
            // LEFT: highest pair p <= c-1
            u64t selhi = 0, sello;
            if (c >= 65) selhi = m1 & (((u64t)1 << (c - 64)) - 1);
            sello = (c <= 63) ? (m0 & (((u64t)1 << c) - 1)) : m0;
            if (selhi)      dL = (float)(c - (127 - __builtin_clzll(selhi))) - 0.5f;
            else if (sello) dL = (float)(c - (63  - __builtin_clzll(sello))) - 0.5f;
            // RIGHT: lowest pair p >= c
            if (c <= 63) {
                u64t r0 = m0 >> c;
                if (r0)      dR = (float)__builtin_ctzll(r0) + 0.5f;
                else if (m1) dR = (float)(64 - c + __builtin_ctzll(m1)) + 0.5f;
            } else {
                u64t r1 = m1 >> (c - 64);
                if (r1)      dR = (float)__builtin_ctzll(r1) + 0.5f;
            }
            float d = fminf(dL, dR);                    // in cell units
            float prox = __expf(-d * (DXC * INV_SIG));

            float sv = st_s[c];
            unsigned short shi = f2bf(sv);
            unsigned short slo = f2bf(sv - bf2f(shi));  // double-bf16 state
            feat_s[swz(lane, wid)]      = shi;
            feat_s[swz(lane, 7 + wid)]  = slo;
            feat_s[swz(lane, 14 + wid)] = f2bf(prox);
        } else if (wid == 7) {
            feat_s[swz(lane, 21)] = f2bf(dtv);
        }
        __syncthreads();   // B: features ready

        // ---- L0 (1x MFMA bf16, K=32): feat x W0'^T -> actA ----
        {
            f32x4 c4 = {0.0f, 0.0f, 0.0f, 0.0f};
            c4 = __builtin_amdgcn_mfma_f32_16x16x32_bf16(
                    *(const bf16x8*)(const void*)&feat_s[(arow << 6) + (((kb0 ^ arow) & 7) << 3)],
                    *(const bf16x8*)(const void*)&w0s   [(brow << 6) + (((kb0 ^ brow) & 7) << 3)], c4, 0, 0, 0);
            float bias = bias0_s[col];
            unsigned u01 = cvt_pk_bf16(fast_gelu(c4[0] + bias), fast_gelu(c4[1] + bias));
            unsigned u23 = cvt_pk_bf16(fast_gelu(c4[2] + bias), fast_gelu(c4[3] + bias));
            actA[swz(row0    , col)] = (unsigned short)u01;
            actA[swz(row0 + 1, col)] = (unsigned short)(u01 >> 16);
            actA[swz(row0 + 2, col)] = (unsigned short)u23;
            actA[swz(row0 + 3, col)] = (unsigned short)(u23 >> 16);
        }
        __syncthreads();   // C: actA ready

        // ---- L1 (MFMA bf16): actA x W1^T -> actB ----
        {
            f32x4 c4 = {0.0f, 0.0f, 0.0f, 0.0f};
            c4 = __builtin_amdgcn_mfma_f32_16x16x32_bf16(
                    *(const bf16x8*)(const void*)&actA[(arow << 6) + (((kb0     ^ arow) & 7) << 3)],
                    *(const bf16x8*)(const void*)&w1s [(brow << 6) + (((kb0     ^ brow) & 7) << 3)], c4, 0, 0, 0);
            c4 = __builtin_amdgcn_mfma_f32_16x16x32_bf16(
                    *(const bf16x8*)(const void*)&actA[(arow << 6) + ((((kb0+4) ^ arow) & 7) << 3)],
                    *(const bf16x8*)(const void*)&w1s [(brow << 6) + ((((kb0+4) ^ brow) & 7) << 3)], c4, 0, 0, 0);
            float bias = bias1_s[col];
            unsigned u01 = cvt_pk_bf16(fast_gelu(c4[0] + bias), fast_gelu(c4[1] + bias));
            unsigned u23 = cvt_pk_bf16(fast_gelu(c4[2] + bias), fast_gelu(c4[3] + bias));
            actB[swz(row0    , col)] = (unsigned short)u01;
            actB[swz(row0 + 1, col)] = (unsigned short)(u01 >> 16);
            actB[swz(row0 + 2, col)] = (unsigned short)u23;
            actB[swz(row0 + 3, col)] = (unsigned short)(u23 >> 16);
        }
        __syncthreads();   // D: actB ready

        // ---- L2 (MFMA bf16) + fused L3 partial (2-stage shfl -> 16/row) ----
        {
            f32x4 c4 = {0.0f, 0.0f, 0.0f, 0.0f};
            c4 = __builtin_amdgcn_mfma_f32_16x16x32_bf16(
                    *(const bf16x8*)(const void*)&actB[(arow << 6) + (((kb0     ^ arow) & 7) << 3)],
                    *(const bf16x8*)(const void*)&w2s [(brow << 6) + (((kb0     ^ brow) & 7) << 3)], c4, 0, 0, 0);
            c4 = __builtin_amdgcn_mfma_f32_16x16x32_bf16(
                    *(const bf16x8*)(const void*)&actB[(arow << 6) + ((((kb0+4) ^ arow) & 7) << 3)],
                    *(const bf16x8*)(const void*)&w2s [(brow << 6) + ((((kb0+4) ^ brow) & 7) << 3)], c4, 0, 0, 0);
            float bias = bias2_s[col];
            float w3c  = w3_s[col];
            #pragma unroll
            for (int j = 0; j < 4; ++j) {
                float p = w3c * fast_gelu(c4[j] + bias);
                p += __shfl_xor(p, 1);
                p += __shfl_xor(p, 2);
                if ((l15 & 3) == 0)
                    part_s[(row0 + j) * 20 + (tn << 2) + (l15 >> 2)] = p;
            }
        }
        __syncthreads();   // E: partials ready

        // ---- wave0: reduce 16 + update + publish (halo first) + store ----
        if (wid == 0) {
            const f32x4* pr = (const f32x4*)(const void*)&part_s[lane * 20];
            f32x4 s4 = pr[0] + pr[1] + pr[2] + pr[3];
            float sum = s4[0] + s4[1] + s4[2] + s4[3];
            float ns = st_s[lane + 32] + r * (sum + b3v);
            ns = fminf(1.0f, fmaxf(0.0f, ns));
            if (t < NT - 1) {
                u64t u = ((u64t)(unsigned)t << 32) |
                         (u64t)(unsigned)__builtin_bit_cast(unsigned, ns);
                sys_store_u64(&halo[(size_t)bid * 128 + (t & 1) * 64 + lane], u);
            }
            st_s[32 + lane] = ns;                  // keep own row resident in LDS
            orow[(size_t)t * NX + gi] = ns;
        }
        // next iter's barrier A guards st_s/feat_s/actA/part_s reuse
    }
}

extern "C" void kernel_launch(void* const* d_in, const int* in_sizes, int n_in,
                              void* d_out, int out_size, void* d_ws, size_t ws_size,
                              hipStream_t stream) {
    const float* grid = (const float*)d_in[0];
    const float* dtp  = (const float*)d_in[1];
    const float* W0   = (const float*)d_in[2];
    const float* b0   = (const float*)d_in[3];
    const float* W1   = (const float*)d_in[4];
    const float* b1   = (const float*)d_in[5];
    const float* W2   = (const float*)d_in[6];
    const float* b2   = (const float*)d_in[7];
    const float* W3   = (const float*)d_in[8];
    const float* b3   = (const float*)d_in[9];
    float* outp = (float*)d_out;

    u64t* halo = (u64t*)d_ws;                     // NBLK * 128 u64 (256 KB)

    // zero the whole halo each launch: tags embedded in data words must not
    // leak across graph replays (stale tag >= need would hand out old rows)
    hipMemsetAsync(d_ws, 0, (size_t)NBLK * 128 * sizeof(u64t), stream);

    void* args[] = {(void*)&grid, (void*)&dtp, (void*)&W0, (void*)&b0,
                    (void*)&W1, (void*)&b1, (void*)&W2, (void*)&b2,
                    (void*)&W3, (void*)&b3, (void*)&outp, (void*)&halo};
    hipLaunchCooperativeKernel((const void*)nfv_kernel,
                               dim3(NBLK), dim3(1024), args, 0, stream);
}